// Round 1
// baseline (441.287 us; speedup 1.0000x reference)
//
#include <hip/hip_runtime.h>
#include <math.h>

#define A_NODES 2048
#define N_NODES 6144
#define H 200

constexpr float INV_PI = 0.31830988618379067f;

__device__ __forceinline__ float wave_reduce_sum(float v) {
  #pragma unroll
  for (int off = 32; off; off >>= 1) v += __shfl_down(v, off, 64);
  return v;
}

__device__ __forceinline__ const float* sel_mod(int m, const float* xa, const float* xv,
                                                const float* xt) {
  return (m == 0) ? xa : ((m == 1) ? xv : xt);
}

// ---------------- K1: per-node inverse L2 norm ----------------
__global__ void norms_k(const float* __restrict__ xa, const float* __restrict__ xv,
                        const float* __restrict__ xt, float* __restrict__ inv_norm) {
  int u = (blockIdx.x * blockDim.x + threadIdx.x) >> 6;
  int lane = threadIdx.x & 63;
  if (u >= N_NODES) return;
  int m = u >> 11, a = u & 2047;
  const float* p = sel_mod(m, xa, xv, xt) + a * H;
  float s = 0.f;
  for (int c = lane; c < H; c += 64) { float v = p[c]; s += v * v; }
  s = wave_reduce_sum(s);
  if (lane == 0) inv_norm[u] = 1.f / sqrtf(s);
}

// ---------------- K2: intra-modal 64x64 angular-similarity blocks ----------------
__global__ void intra_k(const float* __restrict__ xa, const float* __restrict__ xv,
                        const float* __restrict__ xt, const float* __restrict__ inv_norm,
                        float* __restrict__ intra_w) {
  __shared__ float nf[64][201];  // +1 pad: stride 201 words -> conflict-free column reads
  int blk = blockIdx.x;          // m*32 + b
  int m = blk >> 5;
  const float* p = sel_mod(m, xa, xv, xt) + (blk & 31) * 64 * H;
  int u0 = m * A_NODES + (blk & 31) * 64;
  for (int idx = threadIdx.x; idx < 64 * H; idx += 256) {
    int i = idx / H, k = idx - i * H;
    nf[i][k] = p[idx] * inv_norm[u0 + i];
  }
  __syncthreads();
  int i0 = (threadIdx.x >> 4) * 4, j0 = (threadIdx.x & 15) * 4;
  float acc[4][4] = {};
  for (int k = 0; k < H; k++) {
    float av[4], bv[4];
    #pragma unroll
    for (int ii = 0; ii < 4; ii++) av[ii] = nf[i0 + ii][k];
    #pragma unroll
    for (int jj = 0; jj < 4; jj++) bv[jj] = nf[j0 + jj][k];
    #pragma unroll
    for (int ii = 0; ii < 4; ii++)
      #pragma unroll
      for (int jj = 0; jj < 4; jj++) acc[ii][jj] += av[ii] * bv[jj];
  }
  float* outp = intra_w + blk * 4096;
  #pragma unroll
  for (int ii = 0; ii < 4; ii++)
    #pragma unroll
    for (int jj = 0; jj < 4; jj++) {
      float cv = fminf(fmaxf(acc[ii][jj] * 0.99999f, -1.f), 1.f);
      outp[(i0 + ii) * 64 + (j0 + jj)] = 1.f - acosf(cv) * INV_PI;
    }
}

// ---------------- K3: cross-modal diagonal angular similarities ----------------
// pair 0 = (0,1), pair 1 = (0,2), pair 2 = (1,2); cw[pair*2048 + a]
__global__ void crossw_k(const float* __restrict__ xa, const float* __restrict__ xv,
                         const float* __restrict__ xt, const float* __restrict__ inv_norm,
                         float* __restrict__ cw) {
  int g = (blockIdx.x * blockDim.x + threadIdx.x) >> 6;
  int lane = threadIdx.x & 63;
  if (g >= 3 * A_NODES) return;
  int pair = g >> 11, a = g & 2047;
  int m = (pair == 2) ? 1 : 0;
  int n = (pair == 0) ? 1 : 2;
  const float* pm = sel_mod(m, xa, xv, xt) + a * H;
  const float* pn = sel_mod(n, xa, xv, xt) + a * H;
  float s = 0.f;
  for (int c = lane; c < H; c += 64) s += pm[c] * pn[c];
  s = wave_reduce_sum(s);
  if (lane == 0) {
    float cv = s * inv_norm[m * A_NODES + a] * inv_norm[n * A_NODES + a] * 0.99999f;
    cv = fminf(fmaxf(cv, -1.f), 1.f);
    cw[g] = 1.f - acosf(cv) * INV_PI;
  }
}

// ---------------- K4: degree^{-1/2} ----------------
__global__ void dinv_k(const float* __restrict__ intra_w, const float* __restrict__ cw,
                       float* __restrict__ dinv) {
  int u = (blockIdx.x * blockDim.x + threadIdx.x) >> 6;
  int lane = threadIdx.x & 63;
  if (u >= N_NODES) return;
  float v = intra_w[(u >> 6) * 4096 + (u & 63) * 64 + lane];
  v = wave_reduce_sum(v);
  if (lane == 0) {
    int m = u >> 11, a = u & 2047;
    float c1 = (m <= 1) ? cw[a] : cw[A_NODES + a];
    float c2 = (m == 0) ? cw[A_NODES + a] : cw[2 * A_NODES + a];
    dinv[u] = 1.f / sqrtf(v + c1 + c2);
  }
}

// ---------------- shared tiled GEMM core: C[64x64 tile] = A[rows,K] @ B[K,200] ----------------
template <typename FA>
__device__ __forceinline__ void gemm_core(FA fetchA, const float* __restrict__ B, int K,
                                          int r0, int c0, float acc[4][4], float* As,
                                          float* Bs) {
  const int tid = threadIdx.x;
  const int tr4 = (tid >> 4) * 4, tc4 = (tid & 15) * 4;
  const int lr = tid >> 2, lk4 = (tid & 3) * 4;
  const int lkb = tid >> 4, lcb = (tid & 15) * 4;
  const int nkt = (K + 15) >> 4;
  for (int kt = 0; kt < nkt; kt++) {
    const int k0 = kt << 4;
    #pragma unroll
    for (int i = 0; i < 4; i++) {
      int kg = k0 + lk4 + i;
      As[(lk4 + i) * 64 + lr] = (kg < K) ? fetchA(r0 + lr, kg) : 0.f;
    }
    #pragma unroll
    for (int i = 0; i < 4; i++) {
      int kg = k0 + lkb;
      int c = c0 + lcb + i;
      Bs[lkb * 64 + lcb + i] = (kg < K && c < H) ? B[kg * H + c] : 0.f;
    }
    __syncthreads();
    #pragma unroll
    for (int k = 0; k < 16; k++) {
      float4 a4 = *reinterpret_cast<float4*>(As + k * 64 + tr4);
      float4 b4 = *reinterpret_cast<float4*>(Bs + k * 64 + tc4);
      float av[4] = {a4.x, a4.y, a4.z, a4.w};
      float bv[4] = {b4.x, b4.y, b4.z, b4.w};
      #pragma unroll
      for (int ii = 0; ii < 4; ii++)
        #pragma unroll
        for (int jj = 0; jj < 4; jj++) acc[ii][jj] += av[ii] * bv[jj];
    }
    __syncthreads();
  }
}

// ---------------- K5: h0 = relu(big @ fc0_w + b); hs = dinv*h0 ----------------
__global__ void fc0_k(const float* __restrict__ xa, const float* __restrict__ xv,
                      const float* __restrict__ xt, const float* __restrict__ W,
                      const float* __restrict__ bias, const float* __restrict__ dinv,
                      float* __restrict__ h0, float* __restrict__ hs) {
  __shared__ __align__(16) float As[16 * 64];
  __shared__ __align__(16) float Bs[16 * 64];
  int r0 = blockIdx.x * 64, c0 = blockIdx.y * 64;
  float acc[4][4] = {};
  auto fA = [&](int row, int kg) -> float {
    int m = row >> 11, a = row & 2047;
    const float* p = (m == 0) ? xa : ((m == 1) ? xv : xt);
    return p[a * H + kg];
  };
  gemm_core(fA, W, H, r0, c0, acc, As, Bs);
  int tr4 = (threadIdx.x >> 4) * 4, tc4 = (threadIdx.x & 15) * 4;
  #pragma unroll
  for (int ii = 0; ii < 4; ii++) {
    int r = r0 + tr4 + ii;
    float dv = dinv[r];
    #pragma unroll
    for (int jj = 0; jj < 4; jj++) {
      int c = c0 + tc4 + jj;
      if (c < H) {
        float v = fmaxf(acc[ii][jj] + bias[c], 0.f);
        h0[r * H + c] = v;
        hs[r * H + c] = v * dv;
      }
    }
  }
}

// ---------------- K6: hi = adj @ h (block-sparse), wave per row ----------------
__global__ void adj_k(const float* __restrict__ intra_w, const float* __restrict__ cw,
                      const float* __restrict__ dinv, const float* __restrict__ hs,
                      float* __restrict__ hi_out) {
  int u = (blockIdx.x * blockDim.x + threadIdx.x) >> 6;
  int lane = threadIdx.x & 63;
  if (u >= N_NODES) return;
  int m = u >> 11, a = u & 2047, i = u & 63;
  const float* wrow = intra_w + (u >> 6) * 4096 + i * 64;
  int base = u - i;
  float acc0 = 0, acc1 = 0, acc2 = 0, acc3 = 0;
  int c0 = lane, c1 = lane + 64, c2 = lane + 128, c3 = lane + 192;
  bool has3 = (c3 < H);
  for (int j = 0; j < 64; j++) {
    float w = wrow[j];
    const float* hr = hs + (base + j) * H;
    acc0 += w * hr[c0];
    acc1 += w * hr[c1];
    acc2 += w * hr[c2];
    if (has3) acc3 += w * hr[c3];
  }
  int n1, n2, p1, p2;
  if (m == 0)      { n1 = 1; p1 = 0; n2 = 2; p2 = 1; }
  else if (m == 1) { n1 = 0; p1 = 0; n2 = 2; p2 = 2; }
  else             { n1 = 0; p1 = 1; n2 = 1; p2 = 2; }
  float w1 = cw[p1 * A_NODES + a], w2 = cw[p2 * A_NODES + a];
  const float* hr1 = hs + (n1 * A_NODES + a) * H;
  const float* hr2 = hs + (n2 * A_NODES + a) * H;
  acc0 += w1 * hr1[c0] + w2 * hr2[c0];
  acc1 += w1 * hr1[c1] + w2 * hr2[c1];
  acc2 += w1 * hr1[c2] + w2 * hr2[c2];
  if (has3) acc3 += w1 * hr1[c3] + w2 * hr2[c3];
  float d = dinv[u];
  float* op = hi_out + u * H;
  op[c0] = d * acc0;
  op[c1] = d * acc1;
  op[c2] = d * acc2;
  if (has3) op[c3] = d * acc3;
}

// ---------------- K7: GCNII combine: h = relu(beta*([hi,h0]@Wc) + (1-beta)*(0.9 hi + 0.1 h0)) ----------------
__global__ void conv_k(const float* __restrict__ hi, const float* __restrict__ h0,
                       const float* __restrict__ W, const float* __restrict__ dinv,
                       float beta, float* __restrict__ h, float* __restrict__ hs) {
  __shared__ __align__(16) float As[16 * 64];
  __shared__ __align__(16) float Bs[16 * 64];
  int r0 = blockIdx.x * 64, c0 = blockIdx.y * 64;
  float acc[4][4] = {};
  auto fA = [&](int row, int kg) -> float {
    return (kg < H) ? hi[row * H + kg] : h0[row * H + (kg - H)];
  };
  gemm_core(fA, W, 2 * H, r0, c0, acc, As, Bs);
  int tr4 = (threadIdx.x >> 4) * 4, tc4 = (threadIdx.x & 15) * 4;
  float ombeta = 1.f - beta;
  #pragma unroll
  for (int ii = 0; ii < 4; ii++) {
    int r = r0 + tr4 + ii;
    float dv = dinv[r];
    #pragma unroll
    for (int jj = 0; jj < 4; jj++) {
      int c = c0 + tc4 + jj;
      if (c < H) {
        float hiv = hi[r * H + c], h0v = h0[r * H + c];
        float rr = 0.9f * hiv + 0.1f * h0v;
        float v = fmaxf(beta * acc[ii][jj] + ombeta * rr, 0.f);
        h[r * H + c] = v;
        hs[r * H + c] = v * dv;
      }
    }
  }
}

// ---------------- K8: hx[m] = relu([x_m, h_m] @ tm_w[m] + tm_b[m]) ----------------
__global__ void tm_k(const float* __restrict__ xa, const float* __restrict__ xv,
                     const float* __restrict__ xt, const float* __restrict__ hfin,
                     const float* __restrict__ tmw, const float* __restrict__ tmb,
                     float* __restrict__ hx) {
  __shared__ __align__(16) float As[16 * 64];
  __shared__ __align__(16) float Bs[16 * 64];
  int mm = blockIdx.z;
  const float* xm = sel_mod(mm, xa, xv, xt);
  const float* W = tmw + mm * 2 * H * H;
  int r0 = blockIdx.x * 64, c0 = blockIdx.y * 64;
  float acc[4][4] = {};
  auto fA = [&](int row, int kg) -> float {
    return (kg < H) ? xm[row * H + kg] : hfin[(mm * A_NODES + row) * H + (kg - H)];
  };
  gemm_core(fA, W, 2 * H, r0, c0, acc, As, Bs);
  int tr4 = (threadIdx.x >> 4) * 4, tc4 = (threadIdx.x & 15) * 4;
  #pragma unroll
  for (int ii = 0; ii < 4; ii++) {
    int r = r0 + tr4 + ii;
    #pragma unroll
    for (int jj = 0; jj < 4; jj++) {
      int c = c0 + tc4 + jj;
      if (c < H) {
        float v = fmaxf(acc[ii][jj] + tmb[mm * H + c], 0.f);
        hx[(mm * A_NODES + r) * H + c] = v;
      }
    }
  }
}

// ---------------- K9: per-pair gate: part[p] = z*hx_i + (1-z)*hx_j ----------------
__global__ void crossg_k(const float* __restrict__ hx, const float* __restrict__ cw_,
                         const float* __restrict__ cb_, float* __restrict__ part) {
  __shared__ __align__(16) float As[16 * 64];
  __shared__ __align__(16) float Bs[16 * 64];
  int p = blockIdx.z;
  int im = p >> 1;
  int jm = (p & 1) ? ((im == 2) ? 1 : 2) : ((im == 0) ? 1 : 0);
  const float* Hi = hx + im * A_NODES * H;
  const float* Hj = hx + jm * A_NODES * H;
  const float* W = cw_ + p * 3 * H * H;
  const float* bias = cb_ + p * H;
  int r0 = blockIdx.x * 64, c0 = blockIdx.y * 64;
  float acc[4][4] = {};
  auto fA = [&](int row, int kg) -> float {
    if (kg < H) return Hi[row * H + kg];
    if (kg < 2 * H) return Hj[row * H + (kg - H)];
    int k2 = kg - 2 * H;
    return Hi[row * H + k2] * Hj[row * H + k2];
  };
  gemm_core(fA, W, 3 * H, r0, c0, acc, As, Bs);
  int tr4 = (threadIdx.x >> 4) * 4, tc4 = (threadIdx.x & 15) * 4;
  #pragma unroll
  for (int ii = 0; ii < 4; ii++) {
    int r = r0 + tr4 + ii;
    #pragma unroll
    for (int jj = 0; jj < 4; jj++) {
      int c = c0 + tc4 + jj;
      if (c < H) {
        float x = acc[ii][jj] + bias[c];
        float z = 1.f / (1.f + expf(-x));
        float av = Hi[r * H + c], bv = Hj[r * H + c];
        part[p * A_NODES * H + r * H + c] = z * av + (1.f - z) * bv;
      }
    }
  }
}

// ---------------- K10: joint = sum_m (part[2m]+part[2m+1]) @ uni_w[m] + sum_m uni_b[m] ----------------
__global__ void final_k(const float* __restrict__ part, const float* __restrict__ uniw,
                        const float* __restrict__ unib, float* __restrict__ out) {
  int a = (blockIdx.x * blockDim.x + threadIdx.x) >> 6;
  int lane = threadIdx.x & 63;
  if (a >= A_NODES) return;
  float acc[6] = {};
  #pragma unroll
  for (int m = 0; m < 3; m++) {
    const float* pa = part + (2 * m) * A_NODES * H + a * H;
    const float* pb = part + (2 * m + 1) * A_NODES * H + a * H;
    const float* Wm = uniw + m * H * 6;
    for (int c = lane; c < H; c += 64) {
      float v = pa[c] + pb[c];
      #pragma unroll
      for (int t = 0; t < 6; t++) acc[t] += v * Wm[c * 6 + t];
    }
  }
  #pragma unroll
  for (int t = 0; t < 6; t++) {
    #pragma unroll
    for (int off = 32; off; off >>= 1) acc[t] += __shfl_down(acc[t], off, 64);
  }
  if (lane == 0) {
    #pragma unroll
    for (int t = 0; t < 6; t++)
      out[a * 6 + t] = acc[t] + unib[t] + unib[6 + t] + unib[12 + t];
  }
}

extern "C" void kernel_launch(void* const* d_in, const int* in_sizes, int n_in,
                              void* d_out, int out_size, void* d_ws, size_t ws_size,
                              hipStream_t stream) {
  const float* xa = (const float*)d_in[0];
  const float* xv = (const float*)d_in[1];
  const float* xt = (const float*)d_in[2];
  const float* fc0_w = (const float*)d_in[3];
  const float* fc0_b = (const float*)d_in[4];
  const float* conv_w = (const float*)d_in[5];
  const float* tm_w = (const float*)d_in[6];
  const float* tm_b = (const float*)d_in[7];
  const float* cross_w = (const float*)d_in[8];
  const float* cross_b = (const float*)d_in[9];
  const float* uni_w = (const float*)d_in[10];
  const float* uni_b = (const float*)d_in[11];
  float* out = (float*)d_out;
  float* ws = (float*)d_ws;

  // workspace layout (floats); total 6,555,648 floats = 26.2 MB
  float* inv_norm = ws;                 // 6144
  float* dinv = ws + 6144;              // 6144
  float* cw = ws + 12288;               // 6144
  float* intra = ws + 18432;            // 393216  -> 411648
  float* h0 = ws + 411648;              // 1228800 -> 1640448
  float* h = ws + 1640448;              // 1228800 -> 2869248
  float* hs = ws + 2869248;             // 1228800 -> 4098048
  float* hi = ws + 4098048;             // 1228800 -> 5326848
  float* hx = ws + 5326848;             // 1228800 -> 6555648
  float* part = ws + 411648;            // 2457600, overlays h0+h (dead by then)

  norms_k<<<1536, 256, 0, stream>>>(xa, xv, xt, inv_norm);
  intra_k<<<96, 256, 0, stream>>>(xa, xv, xt, inv_norm, intra);
  crossw_k<<<1536, 256, 0, stream>>>(xa, xv, xt, inv_norm, cw);
  dinv_k<<<1536, 256, 0, stream>>>(intra, cw, dinv);
  fc0_k<<<dim3(96, 4), 256, 0, stream>>>(xa, xv, xt, fc0_w, fc0_b, dinv, h0, hs);
  // GCNII layer 0: beta = ln(1.5)
  adj_k<<<1536, 256, 0, stream>>>(intra, cw, dinv, hs, hi);
  conv_k<<<dim3(96, 4), 256, 0, stream>>>(hi, h0, conv_w, dinv, 0.40546510810816444f, h, hs);
  // GCNII layer 1: beta = ln(1.25)
  adj_k<<<1536, 256, 0, stream>>>(intra, cw, dinv, hs, hi);
  conv_k<<<dim3(96, 4), 256, 0, stream>>>(hi, h0, conv_w + 2 * H * H, dinv,
                                          0.22314355131420976f, h, hs);
  tm_k<<<dim3(32, 4, 3), 256, 0, stream>>>(xa, xv, xt, h, tm_w, tm_b, hx);
  crossg_k<<<dim3(32, 4, 6), 256, 0, stream>>>(hx, cross_w, cross_b, part);
  final_k<<<512, 256, 0, stream>>>(part, uni_w, uni_b, out);
}

// Round 4
// 318.252 us; speedup vs baseline: 1.3866x; 1.3866x over previous
//
#include <hip/hip_runtime.h>
#include <math.h>

#define A_NODES 2048
#define N_NODES 6144
#define H 200
#define LDK 40  // padded LDS k-stride (shorts); 80 B rows -> 2-way-free b128 reads

constexpr float INV_PI = 0.31830988618379067f;

typedef __attribute__((ext_vector_type(8))) short bf16x8;
typedef __attribute__((ext_vector_type(4))) float f32x4;
typedef __attribute__((ext_vector_type(4))) short s16x4;

__device__ __forceinline__ short f2bf(float f) {
  unsigned u = __float_as_uint(f);
  u += 0x7FFF + ((u >> 16) & 1);  // round-to-nearest-even
  return (short)(u >> 16);
}

__device__ __forceinline__ float wave_reduce_sum(float v) {
  #pragma unroll
  for (int off = 32; off; off >>= 1) v += __shfl_down(v, off, 64);
  return v;
}

__device__ __forceinline__ const float* sel_mod(int m, const float* xa, const float* xv,
                                                const float* xt) {
  return (m == 0) ? xa : ((m == 1) ? xv : xt);
}

// ---------------- K1: per-node inverse L2 norm ----------------
__global__ void norms_k(const float* __restrict__ xa, const float* __restrict__ xv,
                        const float* __restrict__ xt, float* __restrict__ inv_norm) {
  int u = (blockIdx.x * blockDim.x + threadIdx.x) >> 6;
  int lane = threadIdx.x & 63;
  if (u >= N_NODES) return;
  int m = u >> 11, a = u & 2047;
  const float* p = sel_mod(m, xa, xv, xt) + a * H;
  float s = 0.f;
  for (int c = lane; c < H; c += 64) { float v = p[c]; s += v * v; }
  s = wave_reduce_sum(s);
  if (lane == 0) inv_norm[u] = 1.f / sqrtf(s);
}

// ---------------- K2: intra-modal 64x64 angular-similarity blocks ----------------
__global__ void intra_k(const float* __restrict__ xa, const float* __restrict__ xv,
                        const float* __restrict__ xt, const float* __restrict__ inv_norm,
                        float* __restrict__ intra_w) {
  __shared__ float nf[64][201];
  int blk = blockIdx.x;  // m*32 + b
  int m = blk >> 5;
  const float* p = sel_mod(m, xa, xv, xt) + (blk & 31) * 64 * H;
  int u0 = m * A_NODES + (blk & 31) * 64;
  for (int idx = threadIdx.x; idx < 64 * H; idx += 256) {
    int i = idx / H, k = idx - i * H;
    nf[i][k] = p[idx] * inv_norm[u0 + i];
  }
  __syncthreads();
  int i0 = (threadIdx.x >> 4) * 4, j0 = (threadIdx.x & 15) * 4;
  float acc[4][4] = {};
  for (int k = 0; k < H; k++) {
    float av[4], bv[4];
    #pragma unroll
    for (int ii = 0; ii < 4; ii++) av[ii] = nf[i0 + ii][k];
    #pragma unroll
    for (int jj = 0; jj < 4; jj++) bv[jj] = nf[j0 + jj][k];
    #pragma unroll
    for (int ii = 0; ii < 4; ii++)
      #pragma unroll
      for (int jj = 0; jj < 4; jj++) acc[ii][jj] += av[ii] * bv[jj];
  }
  float* outp = intra_w + blk * 4096;
  #pragma unroll
  for (int ii = 0; ii < 4; ii++)
    #pragma unroll
    for (int jj = 0; jj < 4; jj++) {
      float cv = fminf(fmaxf(acc[ii][jj] * 0.99999f, -1.f), 1.f);
      outp[(i0 + ii) * 64 + (j0 + jj)] = 1.f - acosf(cv) * INV_PI;
    }
}

// ---------------- K3: cross-modal diagonal angular similarities ----------------
__global__ void crossw_k(const float* __restrict__ xa, const float* __restrict__ xv,
                         const float* __restrict__ xt, const float* __restrict__ inv_norm,
                         float* __restrict__ cw) {
  int g = (blockIdx.x * blockDim.x + threadIdx.x) >> 6;
  int lane = threadIdx.x & 63;
  if (g >= 3 * A_NODES) return;
  int pair = g >> 11, a = g & 2047;
  int m = (pair == 2) ? 1 : 0;
  int n = (pair == 0) ? 1 : 2;
  const float* pm = sel_mod(m, xa, xv, xt) + a * H;
  const float* pn = sel_mod(n, xa, xv, xt) + a * H;
  float s = 0.f;
  for (int c = lane; c < H; c += 64) s += pm[c] * pn[c];
  s = wave_reduce_sum(s);
  if (lane == 0) {
    float cv = s * inv_norm[m * A_NODES + a] * inv_norm[n * A_NODES + a] * 0.99999f;
    cv = fminf(fmaxf(cv, -1.f), 1.f);
    cw[g] = 1.f - acosf(cv) * INV_PI;
  }
}

// ---------------- K4: degree^{-1/2} ----------------
__global__ void dinv_k(const float* __restrict__ intra_w, const float* __restrict__ cw,
                       float* __restrict__ dinv) {
  int u = (blockIdx.x * blockDim.x + threadIdx.x) >> 6;
  int lane = threadIdx.x & 63;
  if (u >= N_NODES) return;
  float v = intra_w[(u >> 6) * 4096 + (u & 63) * 64 + lane];
  v = wave_reduce_sum(v);
  if (lane == 0) {
    int m = u >> 11, a = u & 2047;
    float c1 = (m <= 1) ? cw[a] : cw[A_NODES + a];
    float c2 = (m == 0) ? cw[A_NODES + a] : cw[2 * A_NODES + a];
    dinv[u] = 1.f / sqrtf(v + c1 + c2);
  }
}

// ---------------- shared bf16 MFMA GEMM core ----------------
// Block: 256 thr = 4 waves. Tile: 128 rows x 64 cols. Wave w owns rows [w*32,w*32+32).
// acc[i][j]: i in {0,1} row-frag (16 rows), j in 0..3 col-frag (16 cols). K-step 32.
// fetch4(rowLocal, kg) -> float4 of A[r0+rowLocal][kg..kg+3] (zero-padded past K).
template <typename F4>
__device__ __forceinline__ void mfma_core(F4 fetch4, const float* __restrict__ B, int K,
                                          int c0, short* As, short* Bs, f32x4 acc[2][4]) {
  const int tid = threadIdx.x;
  const int arow = tid >> 1, ak0 = (tid & 1) * 16;
  const int bc = tid & 63, bk0 = (tid >> 6) * 8;
  const int w = tid >> 6, l = tid & 63;
  const int fr = l & 15, fk = (l >> 4) * 8;
  const short* ap0 = As + (w * 32 + fr) * LDK + fk;
  const short* bp0 = Bs + fr * LDK + fk;
  const int nkt = (K + 31) >> 5;
  for (int kt = 0; kt < nkt; kt++) {
    const int k0 = kt << 5;
    #pragma unroll
    for (int g = 0; g < 4; g++) {
      float4 v = fetch4(arow, k0 + ak0 + g * 4);
      s16x4 s4 = { f2bf(v.x), f2bf(v.y), f2bf(v.z), f2bf(v.w) };
      *(s16x4*)(As + arow * LDK + ak0 + g * 4) = s4;
    }
    {
      short tmp[8];
      #pragma unroll
      for (int i = 0; i < 8; i++) {
        int kg = k0 + bk0 + i, c = c0 + bc;
        float v = (kg < K && c < H) ? B[kg * H + c] : 0.f;
        tmp[i] = f2bf(v);
      }
      *(s16x4*)(Bs + bc * LDK + bk0) = *(s16x4*)tmp;
      *(s16x4*)(Bs + bc * LDK + bk0 + 4) = *(s16x4*)(tmp + 4);
    }
    __syncthreads();
    bf16x8 a0 = *(const bf16x8*)(ap0);
    bf16x8 a1 = *(const bf16x8*)(ap0 + 16 * LDK);
    bf16x8 b0 = *(const bf16x8*)(bp0);
    bf16x8 b1 = *(const bf16x8*)(bp0 + 16 * LDK);
    bf16x8 b2 = *(const bf16x8*)(bp0 + 32 * LDK);
    bf16x8 b3 = *(const bf16x8*)(bp0 + 48 * LDK);
    acc[0][0] = __builtin_amdgcn_mfma_f32_16x16x32_bf16(a0, b0, acc[0][0], 0, 0, 0);
    acc[0][1] = __builtin_amdgcn_mfma_f32_16x16x32_bf16(a0, b1, acc[0][1], 0, 0, 0);
    acc[0][2] = __builtin_amdgcn_mfma_f32_16x16x32_bf16(a0, b2, acc[0][2], 0, 0, 0);
    acc[0][3] = __builtin_amdgcn_mfma_f32_16x16x32_bf16(a0, b3, acc[0][3], 0, 0, 0);
    acc[1][0] = __builtin_amdgcn_mfma_f32_16x16x32_bf16(a1, b0, acc[1][0], 0, 0, 0);
    acc[1][1] = __builtin_amdgcn_mfma_f32_16x16x32_bf16(a1, b1, acc[1][1], 0, 0, 0);
    acc[1][2] = __builtin_amdgcn_mfma_f32_16x16x32_bf16(a1, b2, acc[1][2], 0, 0, 0);
    acc[1][3] = __builtin_amdgcn_mfma_f32_16x16x32_bf16(a1, b3, acc[1][3], 0, 0, 0);
    __syncthreads();
  }
}

// Epilogue iteration: calls epi(row_local, col, acc_value) for each owned element.
template <typename E>
__device__ __forceinline__ void epilogue(f32x4 acc[2][4], int c0, E epi) {
  const int w = threadIdx.x >> 6, l = threadIdx.x & 63;
  const int fr = l & 15, fq = l >> 4;
  #pragma unroll
  for (int i = 0; i < 2; i++)
    #pragma unroll
    for (int j = 0; j < 4; j++)
      #pragma unroll
      for (int r = 0; r < 4; r++) {
        int rowL = w * 32 + i * 16 + fq * 4 + r;
        int col = c0 + j * 16 + fr;
        if (col < H) epi(rowL, col, acc[i][j][r]);
      }
}

// ---------------- K5: h0 = relu(big @ fc0_w + b); hs = dinv*h0 ----------------
__global__ void fc0_k(const float* __restrict__ xa, const float* __restrict__ xv,
                      const float* __restrict__ xt, const float* __restrict__ W,
                      const float* __restrict__ bias, const float* __restrict__ dinv,
                      float* __restrict__ h0, float* __restrict__ hs) {
  __shared__ __align__(16) short As[128 * LDK];
  __shared__ __align__(16) short Bs[64 * LDK];
  const int r0 = blockIdx.x * 128, c0 = blockIdx.y * 64;
  f32x4 acc[2][4] = {};
  auto f4 = [&](int rowL, int kg) -> float4 {
    if (kg >= H) return make_float4(0.f, 0.f, 0.f, 0.f);
    int row = r0 + rowL;
    int m = row >> 11, a = row & 2047;
    const float* p = (m == 0) ? xa : ((m == 1) ? xv : xt);
    return *(const float4*)(p + a * H + kg);
  };
  mfma_core(f4, W, H, c0, As, Bs, acc);
  epilogue(acc, c0, [&](int rowL, int col, float av) {
    int row = r0 + rowL;
    float v = fmaxf(av + bias[col], 0.f);
    h0[row * H + col] = v;
    hs[row * H + col] = v * dinv[row];
  });
}

// ---------------- K6: hi = adj @ h (block-sparse), wave per row ----------------
__global__ void adj_k(const float* __restrict__ intra_w, const float* __restrict__ cw,
                      const float* __restrict__ dinv, const float* __restrict__ hs,
                      float* __restrict__ hi_out) {
  int u = (blockIdx.x * blockDim.x + threadIdx.x) >> 6;
  int lane = threadIdx.x & 63;
  if (u >= N_NODES) return;
  int m = u >> 11, a = u & 2047, i = u & 63;
  const float* wrow = intra_w + (u >> 6) * 4096 + i * 64;
  int base = u - i;
  float acc0 = 0, acc1 = 0, acc2 = 0, acc3 = 0;
  int c0 = lane, c1 = lane + 64, c2 = lane + 128, c3 = lane + 192;
  bool has3 = (c3 < H);
  for (int j = 0; j < 64; j++) {
    float w = wrow[j];
    const float* hr = hs + (base + j) * H;
    acc0 += w * hr[c0];
    acc1 += w * hr[c1];
    acc2 += w * hr[c2];
    if (has3) acc3 += w * hr[c3];
  }
  int n1, n2, p1, p2;
  if (m == 0)      { n1 = 1; p1 = 0; n2 = 2; p2 = 1; }
  else if (m == 1) { n1 = 0; p1 = 0; n2 = 2; p2 = 2; }
  else             { n1 = 0; p1 = 1; n2 = 1; p2 = 2; }
  float w1 = cw[p1 * A_NODES + a], w2 = cw[p2 * A_NODES + a];
  const float* hr1 = hs + (n1 * A_NODES + a) * H;
  const float* hr2 = hs + (n2 * A_NODES + a) * H;
  acc0 += w1 * hr1[c0] + w2 * hr2[c0];
  acc1 += w1 * hr1[c1] + w2 * hr2[c1];
  acc2 += w1 * hr1[c2] + w2 * hr2[c2];
  if (has3) acc3 += w1 * hr1[c3] + w2 * hr2[c3];
  float d = dinv[u];
  float* op = hi_out + u * H;
  op[c0] = d * acc0;
  op[c1] = d * acc1;
  op[c2] = d * acc2;
  if (has3) op[c3] = d * acc3;
}

// ---------------- K7: GCNII combine ----------------
__global__ void conv_k(const float* __restrict__ hi, const float* __restrict__ h0,
                       const float* __restrict__ W, const float* __restrict__ dinv,
                       float beta, float* __restrict__ h, float* __restrict__ hs) {
  __shared__ __align__(16) short As[128 * LDK];
  __shared__ __align__(16) short Bs[64 * LDK];
  const int r0 = blockIdx.x * 128, c0 = blockIdx.y * 64;
  f32x4 acc[2][4] = {};
  auto f4 = [&](int rowL, int kg) -> float4 {
    int row = r0 + rowL;
    if (kg < H) return *(const float4*)(hi + row * H + kg);
    if (kg < 2 * H) return *(const float4*)(h0 + row * H + (kg - H));
    return make_float4(0.f, 0.f, 0.f, 0.f);
  };
  mfma_core(f4, W, 2 * H, c0, As, Bs, acc);
  float ombeta = 1.f - beta;
  epilogue(acc, c0, [&](int rowL, int col, float av) {
    int row = r0 + rowL;
    float hiv = hi[row * H + col];
    float h0v = h0[row * H + col];
    float rr = 0.9f * hiv + 0.1f * h0v;
    float v = fmaxf(beta * av + ombeta * rr, 0.f);
    h[row * H + col] = v;
    hs[row * H + col] = v * dinv[row];
  });
}

// ---------------- K8: hx[m] = relu([x_m, h_m] @ tm_w[m] + tm_b[m]) ----------------
__global__ void tm_k(const float* __restrict__ xa, const float* __restrict__ xv,
                     const float* __restrict__ xt, const float* __restrict__ hfin,
                     const float* __restrict__ tmw, const float* __restrict__ tmb,
                     float* __restrict__ hx) {
  __shared__ __align__(16) short As[128 * LDK];
  __shared__ __align__(16) short Bs[64 * LDK];
  const int mm = blockIdx.z;
  const float* xm = sel_mod(mm, xa, xv, xt);
  const float* W = tmw + mm * 2 * H * H;
  const int r0 = blockIdx.x * 128, c0 = blockIdx.y * 64;
  f32x4 acc[2][4] = {};
  auto f4 = [&](int rowL, int kg) -> float4 {
    int row = r0 + rowL;
    if (kg < H) return *(const float4*)(xm + row * H + kg);
    if (kg < 2 * H) return *(const float4*)(hfin + (mm * A_NODES + row) * H + (kg - H));
    return make_float4(0.f, 0.f, 0.f, 0.f);
  };
  mfma_core(f4, W, 2 * H, c0, As, Bs, acc);
  epilogue(acc, c0, [&](int rowL, int col, float av) {
    int row = r0 + rowL;
    float v = fmaxf(av + tmb[mm * H + col], 0.f);
    hx[(mm * A_NODES + row) * H + col] = v;
  });
}

// ---------------- K9: per-pair gate ----------------
__global__ void crossg_k(const float* __restrict__ hx, const float* __restrict__ cw_,
                         const float* __restrict__ cb_, float* __restrict__ part) {
  __shared__ __align__(16) short As[128 * LDK];
  __shared__ __align__(16) short Bs[64 * LDK];
  const int p = blockIdx.z;
  const int im = p >> 1;
  const int jm = (p & 1) ? ((im == 2) ? 1 : 2) : ((im == 0) ? 1 : 0);
  const float* Hi = hx + im * A_NODES * H;
  const float* Hj = hx + jm * A_NODES * H;
  const float* W = cw_ + p * 3 * H * H;
  const float* bias = cb_ + p * H;
  const int r0 = blockIdx.x * 128, c0 = blockIdx.y * 64;
  f32x4 acc[2][4] = {};
  auto f4 = [&](int rowL, int kg) -> float4 {
    int row = r0 + rowL;
    if (kg < H) return *(const float4*)(Hi + row * H + kg);
    if (kg < 2 * H) return *(const float4*)(Hj + row * H + (kg - H));
    if (kg < 3 * H) {
      int k2 = kg - 2 * H;
      float4 a = *(const float4*)(Hi + row * H + k2);
      float4 b = *(const float4*)(Hj + row * H + k2);
      return make_float4(a.x * b.x, a.y * b.y, a.z * b.z, a.w * b.w);
    }
    return make_float4(0.f, 0.f, 0.f, 0.f);
  };
  mfma_core(f4, W, 3 * H, c0, As, Bs, acc);
  epilogue(acc, c0, [&](int rowL, int col, float av) {
    int row = r0 + rowL;
    float x = av + bias[col];
    float z = 1.f / (1.f + expf(-x));
    float a = Hi[row * H + col];
    float b = Hj[row * H + col];
    part[p * A_NODES * H + row * H + col] = z * a + (1.f - z) * b;
  });
}

// ---------------- K10: joint projection + modality sum ----------------
__global__ void final_k(const float* __restrict__ part, const float* __restrict__ uniw,
                        const float* __restrict__ unib, float* __restrict__ out) {
  int a = (blockIdx.x * blockDim.x + threadIdx.x) >> 6;
  int lane = threadIdx.x & 63;
  if (a >= A_NODES) return;
  float acc[6] = {};
  #pragma unroll
  for (int m = 0; m < 3; m++) {
    const float* pa = part + (2 * m) * A_NODES * H + a * H;
    const float* pb = part + (2 * m + 1) * A_NODES * H + a * H;
    const float* Wm = uniw + m * H * 6;
    for (int c = lane; c < H; c += 64) {
      float v = pa[c] + pb[c];
      #pragma unroll
      for (int t = 0; t < 6; t++) acc[t] += v * Wm[c * 6 + t];
    }
  }
  #pragma unroll
  for (int t = 0; t < 6; t++) {
    #pragma unroll
    for (int off = 32; off; off >>= 1) acc[t] += __shfl_down(acc[t], off, 64);
  }
  if (lane == 0) {
    #pragma unroll
    for (int t = 0; t < 6; t++)
      out[a * 6 + t] = acc[t] + unib[t] + unib[6 + t] + unib[12 + t];
  }
}

extern "C" void kernel_launch(void* const* d_in, const int* in_sizes, int n_in,
                              void* d_out, int out_size, void* d_ws, size_t ws_size,
                              hipStream_t stream) {
  const float* xa = (const float*)d_in[0];
  const float* xv = (const float*)d_in[1];
  const float* xt = (const float*)d_in[2];
  const float* fc0_w = (const float*)d_in[3];
  const float* fc0_b = (const float*)d_in[4];
  const float* conv_w = (const float*)d_in[5];
  const float* tm_w = (const float*)d_in[6];
  const float* tm_b = (const float*)d_in[7];
  const float* cross_w = (const float*)d_in[8];
  const float* cross_b = (const float*)d_in[9];
  const float* uni_w = (const float*)d_in[10];
  const float* uni_b = (const float*)d_in[11];
  float* out = (float*)d_out;
  float* ws = (float*)d_ws;

  float* inv_norm = ws;                 // 6144
  float* dinv = ws + 6144;              // 6144
  float* cw = ws + 12288;               // 6144
  float* intra = ws + 18432;            // 393216  -> 411648
  float* h0 = ws + 411648;              // 1228800 -> 1640448
  float* h = ws + 1640448;              // 1228800 -> 2869248
  float* hs = ws + 2869248;             // 1228800 -> 4098048
  float* hi = ws + 4098048;             // 1228800 -> 5326848
  float* hx = ws + 5326848;             // 1228800 -> 6555648
  float* part = ws + 411648;            // 2457600, overlays h0+h (dead by then)

  norms_k<<<1536, 256, 0, stream>>>(xa, xv, xt, inv_norm);
  intra_k<<<96, 256, 0, stream>>>(xa, xv, xt, inv_norm, intra);
  crossw_k<<<1536, 256, 0, stream>>>(xa, xv, xt, inv_norm, cw);
  dinv_k<<<1536, 256, 0, stream>>>(intra, cw, dinv);
  fc0_k<<<dim3(48, 4), 256, 0, stream>>>(xa, xv, xt, fc0_w, fc0_b, dinv, h0, hs);
  // GCNII layer 0: beta = ln(1.5)
  adj_k<<<1536, 256, 0, stream>>>(intra, cw, dinv, hs, hi);
  conv_k<<<dim3(48, 4), 256, 0, stream>>>(hi, h0, conv_w, dinv, 0.40546510810816444f, h, hs);
  // GCNII layer 1: beta = ln(1.25)
  adj_k<<<1536, 256, 0, stream>>>(intra, cw, dinv, hs, hi);
  conv_k<<<dim3(48, 4), 256, 0, stream>>>(hi, h0, conv_w + 2 * H * H, dinv,
                                          0.22314355131420976f, h, hs);
  tm_k<<<dim3(16, 4, 3), 256, 0, stream>>>(xa, xv, xt, h, tm_w, tm_b, hx);
  crossg_k<<<dim3(16, 4, 6), 256, 0, stream>>>(hx, cross_w, cross_b, part);
  final_k<<<512, 256, 0, stream>>>(part, uni_w, uni_b, out);
}

// Round 5
// 204.087 us; speedup vs baseline: 2.1623x; 1.5594x over previous
//
#include <hip/hip_runtime.h>
#include <math.h>

#define H 200
constexpr float INV_PI = 0.31830988618379067f;

typedef __attribute__((ext_vector_type(8))) short bf16x8;
typedef __attribute__((ext_vector_type(4))) float f32x4;
typedef __attribute__((ext_vector_type(4))) short s16x4;

__device__ __forceinline__ short f2bf(float f) {
  unsigned u = __float_as_uint(f);
  u += 0x7FFF + ((u >> 16) & 1);  // RNE
  return (short)(u >> 16);
}
__device__ __forceinline__ float bf2f(short s) {
  return __uint_as_float(((unsigned)(unsigned short)s) << 16);
}
__device__ __forceinline__ float wave_reduce_sum(float v) {
  #pragma unroll
  for (int off = 32; off; off >>= 1) v += __shfl_down(v, off, 64);
  return v;
}
__device__ __forceinline__ const float* sel_mod(int m, const float* xa, const float* xv,
                                                const float* xt) {
  return (m == 0) ? xa : ((m == 1) ? xv : xt);
}

// ---- direct-global MFMA core: D[16 arow][64 bcol] per wave, K = NK*32 ----
// A row-major-K bf16 (lda), B row-major-K bf16 (ldb). No LDS, no barriers.
template <int NK>
__device__ __forceinline__ void gemm_dir(const short* __restrict__ A, int lda,
                                         const short* __restrict__ B, int ldb,
                                         f32x4 acc[4]) {
  const int l = threadIdx.x & 63;
  const int fr = l & 15, fk = (l >> 4) * 8;
  const short* ap = A + fr * lda + fk;
  const short* bp = B + fr * ldb + fk;
  const int ldb16 = 16 * ldb, ldb32 = 32 * ldb, ldb48 = 48 * ldb;
  #pragma unroll
  for (int t = 0; t < NK; t++) {
    bf16x8 a  = *(const bf16x8*)(ap);
    bf16x8 b0 = *(const bf16x8*)(bp);
    bf16x8 b1 = *(const bf16x8*)(bp + ldb16);
    bf16x8 b2 = *(const bf16x8*)(bp + ldb32);
    bf16x8 b3 = *(const bf16x8*)(bp + ldb48);
    acc[0] = __builtin_amdgcn_mfma_f32_16x16x32_bf16(a, b0, acc[0], 0, 0, 0);
    acc[1] = __builtin_amdgcn_mfma_f32_16x16x32_bf16(a, b1, acc[1], 0, 0, 0);
    acc[2] = __builtin_amdgcn_mfma_f32_16x16x32_bf16(a, b2, acc[2], 0, 0, 0);
    acc[3] = __builtin_amdgcn_mfma_f32_16x16x32_bf16(a, b3, acc[3], 0, 0, 0);
    ap += 32; bp += 32;
  }
}

// ---------------- pack weights: transposed [outcol][KP] bf16, k-pads zeroed ----------------
__global__ __launch_bounds__(256) void pack_w_k(
    const float* __restrict__ fc0_w, const float* __restrict__ conv_w,
    const float* __restrict__ tm_w, const float* __restrict__ cross_w,
    short* __restrict__ fc0_wt, short* __restrict__ conv_wt,
    short* __restrict__ tm_wt, short* __restrict__ cross_wt) {
  const int S0 = 208 * 224, S1 = 208 * 416, S2 = 208 * 608;
  const int total = S0 + 5 * S1 + 6 * S2;
  for (int idx = blockIdx.x * 256 + threadIdx.x; idx < total; idx += gridDim.x * 256) {
    const float* src; short* dst; int K, KP, rem;
    if (idx < S0) { src = fc0_w; dst = fc0_wt; K = 200; KP = 224; rem = idx; }
    else if (idx < S0 + 2 * S1) {
      rem = idx - S0; int b = rem / S1; rem -= b * S1;
      src = conv_w + b * 400 * 200; dst = conv_wt + b * S1; K = 400; KP = 416;
    } else if (idx < S0 + 5 * S1) {
      rem = idx - S0 - 2 * S1; int b = rem / S1; rem -= b * S1;
      src = tm_w + b * 400 * 200; dst = tm_wt + b * S1; K = 400; KP = 416;
    } else {
      rem = idx - S0 - 5 * S1; int b = rem / S2; rem -= b * S2;
      src = cross_w + b * 600 * 200; dst = cross_wt + b * S2; K = 600; KP = 608;
    }
    int c = rem / KP, k = rem - c * KP;
    float v = (k < K && c < 200) ? src[k * 200 + c] : 0.f;
    dst[c * KP + k] = f2bf(v);
  }
}

// ---------------- pack x -> bigA [6144][224], tmA x-part, zero pads ----------------
__global__ __launch_bounds__(256) void pack_x_k(
    const float* __restrict__ xa, const float* __restrict__ xv, const float* __restrict__ xt,
    short* __restrict__ bigA, short* __restrict__ tmA, short* __restrict__ convA,
    short* __restrict__ crossA) {
  int tid0 = blockIdx.x * 256 + threadIdx.x, stride = gridDim.x * 256;
  for (int idx = tid0; idx < 6144 * 224; idx += stride) {
    int node = idx / 224, k = idx - node * 224;
    float v = 0.f;
    if (k < 200) { int m = node >> 11, a = node & 2047; v = sel_mod(m, xa, xv, xt)[a * H + k]; }
    short s = f2bf(v);
    bigA[idx] = s;
    if (k < 200) tmA[node * 416 + k] = s;
  }
  for (int idx = tid0; idx < 6144 * 16; idx += stride) {
    int node = idx >> 4, i = idx & 15;
    tmA[node * 416 + 400 + i] = 0;
    convA[node * 416 + 400 + i] = 0;
  }
  for (int idx = tid0; idx < 12288 * 8; idx += stride) {
    int row = idx >> 3, i = idx & 7;
    crossA[row * 608 + 600 + i] = 0;
  }
}

// ---------------- norms / crossw / dinv (fp32, unchanged) ----------------
__global__ __launch_bounds__(256) void norms_k(const float* __restrict__ xa,
    const float* __restrict__ xv, const float* __restrict__ xt, float* __restrict__ inv_norm) {
  int u = (blockIdx.x * blockDim.x + threadIdx.x) >> 6;
  int lane = threadIdx.x & 63;
  if (u >= 6144) return;
  int m = u >> 11, a = u & 2047;
  const float* p = sel_mod(m, xa, xv, xt) + a * H;
  float s = 0.f;
  for (int c = lane; c < H; c += 64) { float v = p[c]; s += v * v; }
  s = wave_reduce_sum(s);
  if (lane == 0) inv_norm[u] = 1.f / sqrtf(s);
}

__global__ __launch_bounds__(256) void crossw_k(const float* __restrict__ xa,
    const float* __restrict__ xv, const float* __restrict__ xt,
    const float* __restrict__ inv_norm, float* __restrict__ cw) {
  int g = (blockIdx.x * blockDim.x + threadIdx.x) >> 6;
  int lane = threadIdx.x & 63;
  if (g >= 3 * 2048) return;
  int pair = g >> 11, a = g & 2047;
  int m = (pair == 2) ? 1 : 0;
  int n = (pair == 0) ? 1 : 2;
  const float* pm = sel_mod(m, xa, xv, xt) + a * H;
  const float* pn = sel_mod(n, xa, xv, xt) + a * H;
  float s = 0.f;
  for (int c = lane; c < H; c += 64) s += pm[c] * pn[c];
  s = wave_reduce_sum(s);
  if (lane == 0) {
    float cv = s * inv_norm[m * 2048 + a] * inv_norm[n * 2048 + a] * 0.99999f;
    cv = fminf(fmaxf(cv, -1.f), 1.f);
    cw[g] = 1.f - acosf(cv) * INV_PI;
  }
}

__global__ __launch_bounds__(256) void dinv_k(const float* __restrict__ intra_w,
    const float* __restrict__ cw, float* __restrict__ dinv) {
  int u = (blockIdx.x * blockDim.x + threadIdx.x) >> 6;
  int lane = threadIdx.x & 63;
  if (u >= 6144) return;
  float v = intra_w[(u >> 6) * 4096 + (u & 63) * 64 + lane];
  v = wave_reduce_sum(v);
  if (lane == 0) {
    int m = u >> 11, a = u & 2047;
    float c1 = (m <= 1) ? cw[a] : cw[2048 + a];
    float c2 = (m == 0) ? cw[2048 + a] : cw[2 * 2048 + a];
    dinv[u] = 1.f / sqrtf(v + c1 + c2);
  }
}

// ---------------- intra Gram via MFMA: per (m,b) 64x64 ----------------
__global__ __launch_bounds__(256) void intra_g_k(const short* __restrict__ bigA,
    const float* __restrict__ inv_norm, float* __restrict__ intra, short* __restrict__ intra_b) {
  int mb = blockIdx.x, w = threadIdx.x >> 6;
  f32x4 acc[4] = {};
  gemm_dir<7>(bigA + (mb * 64 + w * 16) * 224, 224, bigA + mb * 64 * 224, 224, acc);
  const int l = threadIdx.x & 63, fr = l & 15, fq = l >> 4;
  int iL0 = w * 16 + fq * 4;
  #pragma unroll
  for (int j = 0; j < 4; j++) {
    int jn = j * 16 + fr;
    float invj = inv_norm[mb * 64 + jn];
    #pragma unroll
    for (int r = 0; r < 4; r++) {
      int iL = iL0 + r;
      float cv = acc[j][r] * inv_norm[mb * 64 + iL] * invj * 0.99999f;
      cv = fminf(fmaxf(cv, -1.f), 1.f);
      float ang = 1.f - acosf(cv) * INV_PI;
      intra[mb * 4096 + iL * 64 + jn] = ang;
      intra_b[mb * 4096 + iL * 64 + jn] = f2bf(ang);
    }
  }
}

// ---------------- fc0: D[c][node] = W^T x; epi: relu+bias -> h0, hs_t, convA ----------------
__global__ __launch_bounds__(256) void fc0_g_k(const short* __restrict__ fc0_wt,
    const short* __restrict__ bigA, const float* __restrict__ bias,
    const float* __restrict__ dinv, float* __restrict__ h0, short* __restrict__ hs_t,
    short* __restrict__ convA) {
  int w = threadIdx.x >> 6;
  int c0 = blockIdx.y * 16;
  int n0 = blockIdx.x * 256 + w * 64;
  f32x4 acc[4] = {};
  gemm_dir<7>(fc0_wt + c0 * 224, 224, bigA + n0 * 224, 224, acc);
  const int l = threadIdx.x & 63, fr = l & 15, fq = l >> 4;
  int cb = c0 + fq * 4;
  if (cb >= 200) return;
  #pragma unroll
  for (int j = 0; j < 4; j++) {
    int node = n0 + j * 16 + fr;
    float dv = dinv[node];
    f32x4 o; s16x4 ob;
    #pragma unroll
    for (int r = 0; r < 4; r++) {
      float v = fmaxf(acc[j][r] + bias[cb + r], 0.f);
      o[r] = v; ob[r] = f2bf(v);
      hs_t[(cb + r) * 6144 + node] = f2bf(v * dv);
    }
    *(f32x4*)(h0 + node * H + cb) = o;
    *(s16x4*)(convA + node * 416 + 200 + cb) = ob;
  }
}

// ---------------- adj: D[c][node] = hs_t x intra_b + cross terms ----------------
__global__ __launch_bounds__(256) void adj_g_k(const short* __restrict__ hs_t,
    const short* __restrict__ intra_b, const float* __restrict__ cw,
    const float* __restrict__ dinv, float* __restrict__ hi, short* __restrict__ convA) {
  int mb = blockIdx.x, w = threadIdx.x >> 6;
  int crow0 = blockIdx.y * 64 + w * 16;
  int nbase = mb * 64;
  f32x4 acc[4] = {};
  gemm_dir<2>(hs_t + crow0 * 6144 + nbase, 6144, intra_b + mb * 4096, 64, acc);
  const int l = threadIdx.x & 63, fr = l & 15, fq = l >> 4;
  int cb = crow0 + fq * 4;
  if (cb >= 200) return;
  int m = mb >> 5;
  int n1, n2, p1, p2;
  if (m == 0)      { n1 = 1; p1 = 0; n2 = 2; p2 = 1; }
  else if (m == 1) { n1 = 0; p1 = 0; n2 = 2; p2 = 2; }
  else             { n1 = 0; p1 = 1; n2 = 1; p2 = 2; }
  #pragma unroll
  for (int j = 0; j < 4; j++) {
    int u = nbase + j * 16 + fr;
    int a = u & 2047;
    float w1 = cw[p1 * 2048 + a], w2 = cw[p2 * 2048 + a];
    float dv = dinv[u];
    int o1 = n1 * 2048 + a, o2 = n2 * 2048 + a;
    f32x4 o; s16x4 ob;
    #pragma unroll
    for (int r = 0; r < 4; r++) {
      int c = cb + r;
      float v = dv * (acc[j][r] + w1 * bf2f(hs_t[c * 6144 + o1]) + w2 * bf2f(hs_t[c * 6144 + o2]));
      o[r] = v; ob[r] = f2bf(v);
    }
    *(f32x4*)(hi + u * H + cb) = o;
    *(s16x4*)(convA + u * 416 + cb) = ob;
  }
}

// ---------------- conv (GCNII combine) ----------------
__global__ __launch_bounds__(256) void conv_g_k(const short* __restrict__ Wt,
    const short* __restrict__ convA, const float* __restrict__ hi, const float* __restrict__ h0,
    const float* __restrict__ dinv, float beta, int writeHs, short* __restrict__ hs_t,
    short* __restrict__ tmA) {
  int w = threadIdx.x >> 6;
  int c0 = blockIdx.y * 16;
  int n0 = blockIdx.x * 256 + w * 64;
  f32x4 acc[4] = {};
  gemm_dir<13>(Wt + c0 * 416, 416, convA + n0 * 416, 416, acc);
  const int l = threadIdx.x & 63, fr = l & 15, fq = l >> 4;
  int cb = c0 + fq * 4;
  if (cb >= 200) return;
  float ombeta = 1.f - beta;
  #pragma unroll
  for (int j = 0; j < 4; j++) {
    int node = n0 + j * 16 + fr;
    f32x4 hiv = *(const f32x4*)(hi + node * H + cb);
    f32x4 h0v = *(const f32x4*)(h0 + node * H + cb);
    float dv = dinv[node];
    #pragma unroll
    for (int r = 0; r < 4; r++) {
      float rr = 0.9f * hiv[r] + 0.1f * h0v[r];
      float v = fmaxf(beta * acc[j][r] + ombeta * rr, 0.f);
      if (writeHs) hs_t[(cb + r) * 6144 + node] = f2bf(v * dv);
      else {
        // collect to bf16x4 below via temp
      }
      if (!writeHs) tmA[node * 416 + 200 + cb + r] = f2bf(v);
    }
  }
}

// ---------------- tm: hx = relu([x,h] @ tm_w + b) ----------------
__global__ __launch_bounds__(256) void tm_g_k(const short* __restrict__ tm_wt,
    const short* __restrict__ tmA, const float* __restrict__ tmb, float* __restrict__ hx) {
  int m = blockIdx.z, w = threadIdx.x >> 6;
  int c0 = blockIdx.y * 16;
  int n0 = blockIdx.x * 256 + w * 64;          // node within modality
  f32x4 acc[4] = {};
  gemm_dir<13>(tm_wt + m * (208 * 416) + c0 * 416, 416, tmA + (m * 2048 + n0) * 416, 416, acc);
  const int l = threadIdx.x & 63, fr = l & 15, fq = l >> 4;
  int cb = c0 + fq * 4;
  if (cb >= 200) return;
  #pragma unroll
  for (int j = 0; j < 4; j++) {
    int node = m * 2048 + n0 + j * 16 + fr;
    f32x4 o;
    #pragma unroll
    for (int r = 0; r < 4; r++) o[r] = fmaxf(acc[j][r] + tmb[m * H + cb + r], 0.f);
    *(f32x4*)(hx + node * H + cb) = o;
  }
}

// ---------------- pack crossA: [hx_i | hx_j | hx_i*hx_j] bf16 ----------------
__global__ __launch_bounds__(256) void pack_cross_k(const float* __restrict__ hx,
    short* __restrict__ crossA) {
  const int jm_t[6] = {1, 2, 0, 2, 0, 1};
  for (int idx = blockIdx.x * 256 + threadIdx.x; idx < 6 * 2048 * 50;
       idx += gridDim.x * 256) {
    int p = idx / (2048 * 50);
    int rem = idx - p * (2048 * 50);
    int node = rem / 50, c = (rem - node * 50) * 4;
    int im = p >> 1, jm = jm_t[p];
    f32x4 a = *(const f32x4*)(hx + (im * 2048 + node) * H + c);
    f32x4 b = *(const f32x4*)(hx + (jm * 2048 + node) * H + c);
    short* dst = crossA + (p * 2048 + node) * 608;
    s16x4 sa, sb, sp;
    #pragma unroll
    for (int r = 0; r < 4; r++) { sa[r] = f2bf(a[r]); sb[r] = f2bf(b[r]); sp[r] = f2bf(a[r] * b[r]); }
    *(s16x4*)(dst + c) = sa;
    *(s16x4*)(dst + 200 + c) = sb;
    *(s16x4*)(dst + 400 + c) = sp;
  }
}

// ---------------- crossg: gate GEMM + sigmoid mix ----------------
__global__ __launch_bounds__(256) void crossg_g_k(const short* __restrict__ cross_wt,
    const short* __restrict__ crossA, const float* __restrict__ cb_,
    const float* __restrict__ hx, float* __restrict__ part) {
  const int jm_t[6] = {1, 2, 0, 2, 0, 1};
  int p = blockIdx.z, w = threadIdx.x >> 6;
  int c0 = blockIdx.y * 16;
  int n0 = blockIdx.x * 256 + w * 64;
  f32x4 acc[4] = {};
  gemm_dir<19>(cross_wt + p * (208 * 608) + c0 * 608, 608,
               crossA + (p * 2048 + n0) * 608, 608, acc);
  const int l = threadIdx.x & 63, fr = l & 15, fq = l >> 4;
  int cb = c0 + fq * 4;
  if (cb >= 200) return;
  int im = p >> 1, jm = jm_t[p];
  #pragma unroll
  for (int j = 0; j < 4; j++) {
    int node = n0 + j * 16 + fr;
    f32x4 av = *(const f32x4*)(hx + (im * 2048 + node) * H + cb);
    f32x4 bv = *(const f32x4*)(hx + (jm * 2048 + node) * H + cb);
    f32x4 o;
    #pragma unroll
    for (int r = 0; r < 4; r++) {
      float x = acc[j][r] + cb_[p * H + cb + r];
      float z = 1.f / (1.f + expf(-x));
      o[r] = z * av[r] + (1.f - z) * bv[r];
    }
    *(f32x4*)(part + (p * 2048 + node) * H + cb) = o;
  }
}

// ---------------- final projection + modality sum ----------------
__global__ __launch_bounds__(256) void final_k(const float* __restrict__ part,
    const float* __restrict__ uniw, const float* __restrict__ unib, float* __restrict__ out) {
  int a = (blockIdx.x * blockDim.x + threadIdx.x) >> 6;
  int lane = threadIdx.x & 63;
  if (a >= 2048) return;
  float acc[6] = {};
  #pragma unroll
  for (int m = 0; m < 3; m++) {
    const float* pa = part + (2 * m) * 2048 * H + a * H;
    const float* pb = part + (2 * m + 1) * 2048 * H + a * H;
    const float* Wm = uniw + m * H * 6;
    for (int c = lane; c < H; c += 64) {
      float v = pa[c] + pb[c];
      #pragma unroll
      for (int t = 0; t < 6; t++) acc[t] += v * Wm[c * 6 + t];
    }
  }
  #pragma unroll
  for (int t = 0; t < 6; t++) {
    #pragma unroll
    for (int off = 32; off; off >>= 1) acc[t] += __shfl_down(acc[t], off, 64);
  }
  if (lane == 0) {
    #pragma unroll
    for (int t = 0; t < 6; t++)
      out[a * 6 + t] = acc[t] + unib[t] + unib[6 + t] + unib[12 + t];
  }
}

extern "C" void kernel_launch(void* const* d_in, const int* in_sizes, int n_in,
                              void* d_out, int out_size, void* d_ws, size_t ws_size,
                              hipStream_t stream) {
  const float* xa = (const float*)d_in[0];
  const float* xv = (const float*)d_in[1];
  const float* xt = (const float*)d_in[2];
  const float* fc0_w = (const float*)d_in[3];
  const float* fc0_b = (const float*)d_in[4];
  const float* conv_w = (const float*)d_in[5];
  const float* tm_w = (const float*)d_in[6];
  const float* tm_b = (const float*)d_in[7];
  const float* cross_w = (const float*)d_in[8];
  const float* cross_b = (const float*)d_in[9];
  const float* uni_w = (const float*)d_in[10];
  const float* uni_b = (const float*)d_in[11];
  float* out = (float*)d_out;
  float* ws = (float*)d_ws;

  // fp32 buffers
  float* inv_norm = ws;                  // 6144
  float* dinv = ws + 6144;               // 6144
  float* cw = ws + 12288;                // 6144
  float* intra = ws + 18432;             // 393216 -> 411648
  float* h0 = ws + 411648;               // 1228800 -> 1640448
  float* hi = ws + 1640448;              // 1228800 -> 2869248
  float* hx = ws + 2869248;              // 1228800 -> 4098048
  float* part = ws + 4098048;            // 2457600 (overlays bigA/convA/tmA region, dead by crossg)
  // bf16 buffers (short*), offsets in floats
  short* bigA = (short*)(ws + 4098048);      // 6144*224 sh = 688128 fl -> 4786176
  short* convA = (short*)(ws + 4786176);     // 6144*416 sh = 1277952 fl -> 6064128
  short* tmA = (short*)(ws + 6064128);       // 1277952 fl -> 7342080
  short* crossA = (short*)(ws + 7342080);    // 6*2048*608 sh = 3735552 fl -> 11077632
  short* hs_t = (short*)(ws + 11077632);     // 256*6144 sh = 786432 fl -> 11864064
  short* intra_b = (short*)(ws + 11864064);  // 393216 sh = 196608 fl -> 12060672
  short* fc0_wt = (short*)(ws + 12060672);   // 208*224 sh = 23296 fl -> 12083968
  short* conv_wt = (short*)(ws + 12083968);  // 2*208*416 sh = 86528 fl -> 12170496
  short* tm_wt = (short*)(ws + 12170496);    // 3*208*416 sh = 129792 fl -> 12300288
  short* cross_wt = (short*)(ws + 12300288); // 6*208*608 sh = 379392 fl -> 12679680
  // total: 12,679,680 floats = 50.7 MB

  pack_w_k<<<2048, 256, 0, stream>>>(fc0_w, conv_w, tm_w, cross_w,
                                     fc0_wt, conv_wt, tm_wt, cross_wt);
  pack_x_k<<<1024, 256, 0, stream>>>(xa, xv, xt, bigA, tmA, convA, crossA);
  norms_k<<<1536, 256, 0, stream>>>(xa, xv, xt, inv_norm);
  crossw_k<<<1536, 256, 0, stream>>>(xa, xv, xt, inv_norm, cw);
  intra_g_k<<<96, 256, 0, stream>>>(bigA, inv_norm, intra, intra_b);
  dinv_k<<<1536, 256, 0, stream>>>(intra, cw, dinv);
  fc0_g_k<<<dim3(24, 13), 256, 0, stream>>>(fc0_wt, bigA, fc0_b, dinv, h0, hs_t, convA);
  // GCNII layer 0
  adj_g_k<<<dim3(96, 4), 256, 0, stream>>>(hs_t, intra_b, cw, dinv, hi, convA);
  conv_g_k<<<dim3(24, 13), 256, 0, stream>>>(conv_wt, convA, hi, h0, dinv,
                                             0.40546510810816444f, 1, hs_t, tmA);
  // GCNII layer 1
  adj_g_k<<<dim3(96, 4), 256, 0, stream>>>(hs_t, intra_b, cw, dinv, hi, convA);
  conv_g_k<<<dim3(24, 13), 256, 0, stream>>>(conv_wt + 208 * 416, convA, hi, h0, dinv,
                                             0.22314355131420976f, 0, hs_t, tmA);
  tm_g_k<<<dim3(8, 13, 3), 256, 0, stream>>>(tm_wt, tmA, tm_b, hx);
  pack_cross_k<<<2048, 256, 0, stream>>>(hx, crossA);
  crossg_g_k<<<dim3(8, 13, 6), 256, 0, stream>>>(cross_wt, crossA, cross_b, hx, part);
  final_k<<<512, 256, 0, stream>>>(part, uni_w, uni_b, out);
}

// Round 6
// 177.567 us; speedup vs baseline: 2.4852x; 1.1494x over previous
//
#include <hip/hip_runtime.h>
#include <math.h>

#define H 200
constexpr float INV_PI = 0.31830988618379067f;

typedef __attribute__((ext_vector_type(8))) short bf16x8;
typedef __attribute__((ext_vector_type(4))) float f32x4;
typedef __attribute__((ext_vector_type(4))) short s16x4;

__device__ __forceinline__ short f2bf(float f) {
  unsigned u = __float_as_uint(f);
  u += 0x7FFF + ((u >> 16) & 1);  // RNE
  return (short)(u >> 16);
}
__device__ __forceinline__ float bf2f(short s) {
  return __uint_as_float(((unsigned)(unsigned short)s) << 16);
}
__device__ __forceinline__ float angsim(float c) {
  c = fminf(fmaxf(c * 0.99999f, -1.f), 1.f);
  return 1.f - acosf(c) * INV_PI;
}
__device__ __forceinline__ const float* sel_mod(int m, const float* xa, const float* xv,
                                                const float* xt) {
  return (m == 0) ? xa : ((m == 1) ? xv : xt);
}

// ---- 16x16 per-wave MFMA core: D[16 c][16 node], K = NK*32, direct global ----
template <int NK>
__device__ __forceinline__ void gemm1(const short* __restrict__ A, int lda,
                                      const short* __restrict__ B, int ldb, f32x4& acc) {
  const int l = threadIdx.x & 63;
  const short* ap = A + (l & 15) * lda + (l >> 4) * 8;
  const short* bp = B + (l & 15) * ldb + (l >> 4) * 8;
  #pragma unroll
  for (int t = 0; t < NK; t++) {
    bf16x8 a = *(const bf16x8*)(ap + t * 32);
    bf16x8 b = *(const bf16x8*)(bp + t * 32);
    acc = __builtin_amdgcn_mfma_f32_16x16x32_bf16(a, b, acc, 0, 0, 0);
  }
}

// ---- 16x64 per-wave core (intra Gram): 4 B-frags ----
template <int NK>
__device__ __forceinline__ void gemm4(const short* __restrict__ A, int lda,
                                      const short* __restrict__ B, int ldb, f32x4 acc[4]) {
  const int l = threadIdx.x & 63;
  const short* ap = A + (l & 15) * lda + (l >> 4) * 8;
  const short* bp = B + (l & 15) * ldb + (l >> 4) * 8;
  const int o16 = 16 * ldb, o32 = 32 * ldb, o48 = 48 * ldb;
  #pragma unroll
  for (int t = 0; t < NK; t++) {
    bf16x8 a = *(const bf16x8*)(ap + t * 32);
    bf16x8 b0 = *(const bf16x8*)(bp + t * 32);
    bf16x8 b1 = *(const bf16x8*)(bp + o16 + t * 32);
    bf16x8 b2 = *(const bf16x8*)(bp + o32 + t * 32);
    bf16x8 b3 = *(const bf16x8*)(bp + o48 + t * 32);
    acc[0] = __builtin_amdgcn_mfma_f32_16x16x32_bf16(a, b0, acc[0], 0, 0, 0);
    acc[1] = __builtin_amdgcn_mfma_f32_16x16x32_bf16(a, b1, acc[1], 0, 0, 0);
    acc[2] = __builtin_amdgcn_mfma_f32_16x16x32_bf16(a, b2, acc[2], 0, 0, 0);
    acc[3] = __builtin_amdgcn_mfma_f32_16x16x32_bf16(a, b3, acc[3], 0, 0, 0);
  }
}

// ================= K1: prologue — pack weights + pack x + norms + cross sims =================
__global__ __launch_bounds__(256) void pre_k(
    const float* __restrict__ xa, const float* __restrict__ xv, const float* __restrict__ xt,
    const float* __restrict__ fc0_w, const float* __restrict__ conv_w,
    const float* __restrict__ tm_w, const float* __restrict__ cross_w,
    short* __restrict__ fc0_wt, short* __restrict__ conv_wt, short* __restrict__ tm_wt,
    short* __restrict__ cross_wt, short* __restrict__ bigA, short* __restrict__ tmA,
    short* __restrict__ convA, short* __restrict__ hxb,
    float* __restrict__ inv_norm, float* __restrict__ cw) {
  const int lane = threadIdx.x & 63;
  const int wid = blockIdx.x * 4 + (threadIdx.x >> 6);  // 0..8191

  if (wid < 6144) {  // per-node: norm + pack bigA/tmA rows + pads
    int u = wid, m = u >> 11, a = u & 2047;
    const float* p = sel_mod(m, xa, xv, xt) + a * H;
    float v0 = p[lane], v1 = p[lane + 64], v2 = p[lane + 128];
    float v3 = (lane < 8) ? p[lane + 192] : 0.f;
    float s = v0 * v0 + v1 * v1 + v2 * v2 + v3 * v3;
    #pragma unroll
    for (int off = 32; off; off >>= 1) s += __shfl_down(s, off, 64);
    if (lane == 0) inv_norm[u] = 1.f / sqrtf(s);
    short b0 = f2bf(v0), b1 = f2bf(v1), b2 = f2bf(v2), b3 = f2bf(v3);
    short* br = bigA + u * 224;
    br[lane] = b0; br[lane + 64] = b1; br[lane + 128] = b2;
    if (lane < 32) br[192 + lane] = (lane < 8) ? b3 : (short)0;
    short* tr = tmA + u * 416;
    tr[lane] = b0; tr[lane + 64] = b1; tr[lane + 128] = b2;
    if (lane < 8) tr[192 + lane] = b3;
    if (lane < 16) { tr[400 + lane] = 0; convA[u * 416 + 400 + lane] = 0; }
    if (lane < 24) hxb[u * 224 + 200 + lane] = 0;
  } else if (wid < 8192) {  // per-utterance cross-modal sims (self-contained)
    int a = wid - 6144;
    const float* pa = xa + a * H;
    const float* pv = xv + a * H;
    const float* pt = xt + a * H;
    float a0 = pa[lane], a1 = pa[lane + 64], a2 = pa[lane + 128],
          a3 = (lane < 8) ? pa[lane + 192] : 0.f;
    float q0 = pv[lane], q1 = pv[lane + 64], q2 = pv[lane + 128],
          q3 = (lane < 8) ? pv[lane + 192] : 0.f;
    float t0 = pt[lane], t1 = pt[lane + 64], t2 = pt[lane + 128],
          t3 = (lane < 8) ? pt[lane + 192] : 0.f;
    float red[6];
    red[0] = a0 * a0 + a1 * a1 + a2 * a2 + a3 * a3;
    red[1] = q0 * q0 + q1 * q1 + q2 * q2 + q3 * q3;
    red[2] = t0 * t0 + t1 * t1 + t2 * t2 + t3 * t3;
    red[3] = a0 * q0 + a1 * q1 + a2 * q2 + a3 * q3;
    red[4] = a0 * t0 + a1 * t1 + a2 * t2 + a3 * t3;
    red[5] = q0 * t0 + q1 * t1 + q2 * t2 + q3 * t3;
    #pragma unroll
    for (int off = 32; off; off >>= 1)
      #pragma unroll
      for (int q = 0; q < 6; q++) red[q] += __shfl_down(red[q], off, 64);
    if (lane == 0) {
      float ia = 1.f / sqrtf(red[0]), iv = 1.f / sqrtf(red[1]), it = 1.f / sqrtf(red[2]);
      cw[a] = angsim(red[3] * ia * iv);
      cw[2048 + a] = angsim(red[4] * ia * it);
      cw[4096 + a] = angsim(red[5] * iv * it);
    }
  }

  // weight packing (grid-stride over all blocks)
  const int S0 = 208 * 224, S1 = 208 * 416, S2 = 3 * 208 * 224;
  const int totalW = S0 + 5 * S1 + 6 * S2;
  for (int idx = blockIdx.x * 256 + threadIdx.x; idx < totalW; idx += gridDim.x * 256) {
    if (idx < S0) {
      int c = idx / 224, k = idx - c * 224;
      fc0_wt[idx] = (k < 200 && c < 200) ? f2bf(fc0_w[k * 200 + c]) : (short)0;
    } else if (idx < S0 + 5 * S1) {
      int rem = idx - S0;
      int b = rem / S1; rem -= b * S1;
      int c = rem / 416, k = rem - c * 416;
      const float* src; short* dst;
      if (b < 2) { src = conv_w + b * 80000; dst = conv_wt + b * S1; }
      else { src = tm_w + (b - 2) * 80000; dst = tm_wt + (b - 2) * S1; }
      dst[c * 416 + k] = (k < 400 && c < 200) ? f2bf(src[k * 200 + c]) : (short)0;
    } else {
      int rem = idx - S0 - 5 * S1;
      int p = rem / S2; rem -= p * S2;
      int ph = rem / (208 * 224); rem -= ph * (208 * 224);
      int c = rem / 224, k = rem - c * 224;
      cross_wt[((p * 3 + ph) * 208 + c) * 224 + k] =
          (k < 200 && c < 200) ? f2bf(cross_w[p * 120000 + (ph * 200 + k) * 200 + c]) : (short)0;
    }
  }
}

// ================= K2: intra Gram (bf16 MFMA) + fused dinv =================
__global__ __launch_bounds__(256) void intra_g_k(const short* __restrict__ bigA,
    const float* __restrict__ inv_norm, const float* __restrict__ cw,
    short* __restrict__ intra_b, float* __restrict__ dinv) {
  const int mb = blockIdx.x, w = threadIdx.x >> 6;
  f32x4 acc[4] = {};
  gemm4<7>(bigA + (mb * 64 + w * 16) * 224, 224, bigA + mb * 64 * 224, 224, acc);
  const int l = threadIdx.x & 63, fr = l & 15, fq = l >> 4;
  const int iL0 = w * 16 + fq * 4, u0 = mb * 64;
  float rsum[4] = {0.f, 0.f, 0.f, 0.f};
  #pragma unroll
  for (int j = 0; j < 4; j++) {
    int jn = j * 16 + fr;
    float invj = inv_norm[u0 + jn];
    #pragma unroll
    for (int r = 0; r < 4; r++) {
      float ang = angsim(acc[j][r] * inv_norm[u0 + iL0 + r] * invj);
      intra_b[mb * 4096 + (iL0 + r) * 64 + jn] = f2bf(ang);
      rsum[r] += ang;
    }
  }
  #pragma unroll
  for (int mask = 1; mask < 16; mask <<= 1)
    #pragma unroll
    for (int r = 0; r < 4; r++) rsum[r] += __shfl_xor(rsum[r], mask, 64);
  if (fr == 0) {
    int m = u0 >> 11;
    #pragma unroll
    for (int r = 0; r < 4; r++) {
      int u = u0 + iL0 + r, a = u & 2047;
      float c1 = (m <= 1) ? cw[a] : cw[2048 + a];
      float c2 = (m == 0) ? cw[2048 + a] : cw[4096 + a];
      dinv[u] = 1.f / sqrtf(rsum[r] + c1 + c2);
    }
  }
}

// ================= K3: fc0 =================
__global__ __launch_bounds__(256) void fc0_g_k(const short* __restrict__ fc0_wt,
    const short* __restrict__ bigA, const float* __restrict__ bias,
    const float* __restrict__ dinv, short* __restrict__ convA, short* __restrict__ hs_t) {
  const int w = threadIdx.x >> 6;
  const int c0 = blockIdx.y * 16;
  const int n0 = (blockIdx.x * 4 + w) * 16;
  f32x4 acc = {};
  gemm1<7>(fc0_wt + c0 * 224, 224, bigA + n0 * 224, 224, acc);
  const int l = threadIdx.x & 63;
  const int node = n0 + (l & 15), cb = c0 + (l >> 4) * 4;
  if (cb >= 200) return;
  float dv = dinv[node];
  s16x4 oh;
  #pragma unroll
  for (int r = 0; r < 4; r++) {
    float v = fmaxf(acc[r] + bias[cb + r], 0.f);
    oh[r] = f2bf(v);
    hs_t[(cb + r) * 6144 + node] = f2bf(v * dv);
  }
  *(s16x4*)(convA + node * 416 + 200 + cb) = oh;
}

// ================= K4/K6: adj (block-sparse A-hat @ h) =================
__global__ __launch_bounds__(256) void adj_g_k(const short* __restrict__ hs_t,
    const short* __restrict__ intra_b, const float* __restrict__ cw,
    const float* __restrict__ dinv, short* __restrict__ convA) {
  const int mb = blockIdx.x, w = threadIdx.x >> 6;
  const int c0 = blockIdx.y * 16;
  const int nbase = mb * 64, ug = w * 16;
  f32x4 acc = {};
  gemm1<2>(hs_t + c0 * 6144 + nbase, 6144, intra_b + mb * 4096 + ug * 64, 64, acc);
  const int l = threadIdx.x & 63;
  const int u = nbase + ug + (l & 15), cb = c0 + (l >> 4) * 4;
  if (cb >= 200) return;
  const int m = u >> 11, a = u & 2047;
  int n1, n2, p1, p2;
  if (m == 0)      { n1 = 1; p1 = 0; n2 = 2; p2 = 1; }
  else if (m == 1) { n1 = 0; p1 = 0; n2 = 2; p2 = 2; }
  else             { n1 = 0; p1 = 1; n2 = 1; p2 = 2; }
  float w1 = cw[p1 * 2048 + a], w2 = cw[p2 * 2048 + a];
  float dv = dinv[u];
  int o1 = n1 * 2048 + a, o2 = n2 * 2048 + a;
  s16x4 o;
  #pragma unroll
  for (int r = 0; r < 4; r++) {
    int c = cb + r;
    float v = dv * (acc[r] + w1 * bf2f(hs_t[c * 6144 + o1]) + w2 * bf2f(hs_t[c * 6144 + o2]));
    o[r] = f2bf(v);
  }
  *(s16x4*)(convA + u * 416 + cb) = o;
}

// ================= K5/K7: GCNII combine =================
__global__ __launch_bounds__(256) void conv_g_k(const short* __restrict__ Wt,
    const short* __restrict__ convA, const float* __restrict__ dinv, float beta,
    int writeHs, short* __restrict__ hs_t, short* __restrict__ tmA) {
  const int w = threadIdx.x >> 6;
  const int c0 = blockIdx.y * 16;
  const int n0 = (blockIdx.x * 4 + w) * 16;
  f32x4 acc = {};
  gemm1<13>(Wt + c0 * 416, 416, convA + n0 * 416, 416, acc);
  const int l = threadIdx.x & 63;
  const int node = n0 + (l & 15), cb = c0 + (l >> 4) * 4;
  if (cb >= 200) return;
  s16x4 hiv = *(const s16x4*)(convA + node * 416 + cb);
  s16x4 h0v = *(const s16x4*)(convA + node * 416 + 200 + cb);
  float ombeta = 1.f - beta;
  if (writeHs) {
    float dv = dinv[node];
    #pragma unroll
    for (int r = 0; r < 4; r++) {
      float rr = 0.9f * bf2f(hiv[r]) + 0.1f * bf2f(h0v[r]);
      float v = fmaxf(beta * acc[r] + ombeta * rr, 0.f);
      hs_t[(cb + r) * 6144 + node] = f2bf(v * dv);
    }
  } else {
    s16x4 o;
    #pragma unroll
    for (int r = 0; r < 4; r++) {
      float rr = 0.9f * bf2f(hiv[r]) + 0.1f * bf2f(h0v[r]);
      float v = fmaxf(beta * acc[r] + ombeta * rr, 0.f);
      o[r] = f2bf(v);
    }
    *(s16x4*)(tmA + node * 416 + 200 + cb) = o;
  }
}

// ================= K8: tm =================
__global__ __launch_bounds__(256) void tm_g_k(const short* __restrict__ tm_wt,
    const short* __restrict__ tmA, const float* __restrict__ tmb, short* __restrict__ hxb) {
  const int m = blockIdx.z, w = threadIdx.x >> 6;
  const int c0 = blockIdx.y * 16;
  const int n0 = (blockIdx.x * 4 + w) * 16;
  f32x4 acc = {};
  gemm1<13>(tm_wt + m * (208 * 416) + c0 * 416, 416, tmA + (m * 2048 + n0) * 416, 416, acc);
  const int l = threadIdx.x & 63;
  const int node = n0 + (l & 15), cb = c0 + (l >> 4) * 4;
  if (cb >= 200) return;
  s16x4 o;
  #pragma unroll
  for (int r = 0; r < 4; r++) o[r] = f2bf(fmaxf(acc[r] + tmb[m * H + cb + r], 0.f));
  *(s16x4*)(hxb + (m * 2048 + node) * 224 + cb) = o;
}

// ================= K9: cross gate (3-phase) + fused final projection =================
__global__ __launch_bounds__(256) void crossg_g_k(const short* __restrict__ cross_wt,
    const short* __restrict__ hxb, const float* __restrict__ cb_,
    const float* __restrict__ uniw, const float* __restrict__ unib, float* __restrict__ out) {
  const int jm_t[6] = {1, 2, 0, 2, 0, 1};
  const int p = blockIdx.z, w = threadIdx.x >> 6;
  const int im = p >> 1, jm = jm_t[p];
  const int c0 = blockIdx.y * 16;
  const int n0 = (blockIdx.x * 4 + w) * 16;
  const short* Wp = cross_wt + p * (3 * 208 * 224);
  const short* Bi = hxb + (im * 2048 + n0) * 224;
  const short* Bj = hxb + (jm * 2048 + n0) * 224;
  f32x4 acc = {};
  gemm1<7>(Wp + c0 * 224, 224, Bi, 224, acc);
  gemm1<7>(Wp + 208 * 224 + c0 * 224, 224, Bj, 224, acc);
  {  // phase 2: product operand computed inline
    const int l = threadIdx.x & 63;
    const short* ap = Wp + 2 * 208 * 224 + (c0 + (l & 15)) * 224 + (l >> 4) * 8;
    const short* bpi = Bi + (l & 15) * 224 + (l >> 4) * 8;
    const short* bpj = Bj + (l & 15) * 224 + (l >> 4) * 8;
    #pragma unroll
    for (int t = 0; t < 7; t++) {
      bf16x8 a = *(const bf16x8*)(ap + t * 32);
      bf16x8 bi = *(const bf16x8*)(bpi + t * 32);
      bf16x8 bj = *(const bf16x8*)(bpj + t * 32);
      bf16x8 pr;
      #pragma unroll
      for (int e = 0; e < 8; e++) pr[e] = f2bf(bf2f(bi[e]) * bf2f(bj[e]));
      acc = __builtin_amdgcn_mfma_f32_16x16x32_bf16(a, pr, acc, 0, 0, 0);
    }
  }
  const int l = threadIdx.x & 63;
  const int node = n0 + (l & 15), cb = c0 + (l >> 4) * 4;
  float pt[6] = {0.f, 0.f, 0.f, 0.f, 0.f, 0.f};
  if (cb < 200) {
    s16x4 ai = *(const s16x4*)(hxb + (im * 2048 + node) * 224 + cb);
    s16x4 aj = *(const s16x4*)(hxb + (jm * 2048 + node) * 224 + cb);
    const float* Wu = uniw + im * (H * 6);
    #pragma unroll
    for (int r = 0; r < 4; r++) {
      float x = acc[r] + cb_[p * H + cb + r];
      float z = 1.f / (1.f + expf(-x));
      float o = z * bf2f(ai[r]) + (1.f - z) * bf2f(aj[r]);
      #pragma unroll
      for (int t = 0; t < 6; t++) pt[t] += o * Wu[(cb + r) * 6 + t];
    }
  }
  #pragma unroll
  for (int t = 0; t < 6; t++) {
    pt[t] += __shfl_xor(pt[t], 16, 64);
    pt[t] += __shfl_xor(pt[t], 32, 64);
  }
  if ((l >> 4) == 0) {
    if (p == 0 && blockIdx.y == 0) {
      #pragma unroll
      for (int t = 0; t < 6; t++) pt[t] += unib[t] + unib[6 + t] + unib[12 + t];
    }
    #pragma unroll
    for (int t = 0; t < 6; t++) atomicAdd(out + node * 6 + t, pt[t]);
  }
}

extern "C" void kernel_launch(void* const* d_in, const int* in_sizes, int n_in,
                              void* d_out, int out_size, void* d_ws, size_t ws_size,
                              hipStream_t stream) {
  const float* xa = (const float*)d_in[0];
  const float* xv = (const float*)d_in[1];
  const float* xt = (const float*)d_in[2];
  const float* fc0_w = (const float*)d_in[3];
  const float* fc0_b = (const float*)d_in[4];
  const float* conv_w = (const float*)d_in[5];
  const float* tm_w = (const float*)d_in[6];
  const float* tm_b = (const float*)d_in[7];
  const float* cross_w = (const float*)d_in[8];
  const float* cross_b = (const float*)d_in[9];
  const float* uni_w = (const float*)d_in[10];
  const float* uni_b = (const float*)d_in[11];
  float* out = (float*)d_out;
  float* ws = (float*)d_ws;

  // workspace (float offsets)
  float* inv_norm = ws;                       // 6144
  float* dinv = ws + 6144;                    // 6144
  float* cw = ws + 12288;                     // 6144
  short* bigA = (short*)(ws + 18432);         // 6144*224 sh -> +688128 = 706560
  short* convA = (short*)(ws + 706560);       // 6144*416 sh -> +1277952 = 1984512
  short* tmA = (short*)(ws + 1984512);        // 6144*416 sh -> 3262464
  short* hxb = (short*)(ws + 3262464);        // 6144*224 sh -> 3950592
  short* hs_t = (short*)(ws + 3950592);       // 208*6144 sh -> 4589568
  short* intra_b = (short*)(ws + 4589568);    // 96*4096 sh -> 4786176
  short* fc0_wt = (short*)(ws + 4786176);     // 208*224 sh -> 4809472
  short* conv_wt = (short*)(ws + 4809472);    // 2*208*416 sh -> 4896000
  short* tm_wt = (short*)(ws + 4896000);      // 3*208*416 sh -> 5025792
  short* cross_wt = (short*)(ws + 5025792);   // 6*3*208*224 sh -> 5445120 (21.8 MB)

  hipMemsetAsync(out, 0, (size_t)out_size * sizeof(float), stream);
  pre_k<<<2048, 256, 0, stream>>>(xa, xv, xt, fc0_w, conv_w, tm_w, cross_w,
                                  fc0_wt, conv_wt, tm_wt, cross_wt,
                                  bigA, tmA, convA, hxb, inv_norm, cw);
  intra_g_k<<<96, 256, 0, stream>>>(bigA, inv_norm, cw, intra_b, dinv);
  fc0_g_k<<<dim3(96, 13), 256, 0, stream>>>(fc0_wt, bigA, fc0_b, dinv, convA, hs_t);
  adj_g_k<<<dim3(96, 13), 256, 0, stream>>>(hs_t, intra_b, cw, dinv, convA);
  conv_g_k<<<dim3(96, 13), 256, 0, stream>>>(conv_wt, convA, dinv,
                                             0.40546510810816444f, 1, hs_t, tmA);
  adj_g_k<<<dim3(96, 13), 256, 0, stream>>>(hs_t, intra_b, cw, dinv, convA);
  conv_g_k<<<dim3(96, 13), 256, 0, stream>>>(conv_wt + 208 * 416, convA, dinv,
                                             0.22314355131420976f, 0, hs_t, tmA);
  tm_g_k<<<dim3(32, 13, 3), 256, 0, stream>>>(tm_wt, tmA, tm_b, hxb);
  crossg_g_k<<<dim3(32, 13, 6), 256, 0, stream>>>(cross_wt, hxb, cross_b, uni_w, uni_b, out);
}

// Round 7
// 172.834 us; speedup vs baseline: 2.5532x; 1.0274x over previous
//
#include <hip/hip_runtime.h>
#include <math.h>

#define H 200
constexpr float INV_PI = 0.31830988618379067f;

typedef __attribute__((ext_vector_type(8))) short bf16x8;
typedef __attribute__((ext_vector_type(4))) float f32x4;
typedef __attribute__((ext_vector_type(4))) short s16x4;

__device__ __forceinline__ short f2bf(float f) {
  unsigned u = __float_as_uint(f);
  u += 0x7FFF + ((u >> 16) & 1);  // RNE
  return (short)(u >> 16);
}
__device__ __forceinline__ float bf2f(short s) {
  return __uint_as_float(((unsigned)(unsigned short)s) << 16);
}
__device__ __forceinline__ float angsim(float c) {
  c = fminf(fmaxf(c * 0.99999f, -1.f), 1.f);
  return 1.f - acosf(c) * INV_PI;
}
__device__ __forceinline__ const float* sel_mod(int m, const float* xa, const float* xv,
                                                const float* xt) {
  return (m == 0) ? xa : ((m == 1) ? xv : xt);
}

// ---- 16x16 per-wave MFMA core: D[16 m][16 n], K = NK*32, direct global ----
template <int NK>
__device__ __forceinline__ void gemm1(const short* __restrict__ A, int lda,
                                      const short* __restrict__ B, int ldb, f32x4& acc) {
  const int l = threadIdx.x & 63;
  const short* ap = A + (l & 15) * lda + (l >> 4) * 8;
  const short* bp = B + (l & 15) * ldb + (l >> 4) * 8;
  #pragma unroll
  for (int t = 0; t < NK; t++) {
    bf16x8 a = *(const bf16x8*)(ap + t * 32);
    bf16x8 b = *(const bf16x8*)(bp + t * 32);
    acc = __builtin_amdgcn_mfma_f32_16x16x32_bf16(a, b, acc, 0, 0, 0);
  }
}

// ---- 16x64 per-wave core (intra Gram): 4 B-frags ----
template <int NK>
__device__ __forceinline__ void gemm4(const short* __restrict__ A, int lda,
                                      const short* __restrict__ B, int ldb, f32x4 acc[4]) {
  const int l = threadIdx.x & 63;
  const short* ap = A + (l & 15) * lda + (l >> 4) * 8;
  const short* bp = B + (l & 15) * ldb + (l >> 4) * 8;
  const int o16 = 16 * ldb, o32 = 32 * ldb, o48 = 48 * ldb;
  #pragma unroll
  for (int t = 0; t < NK; t++) {
    bf16x8 a = *(const bf16x8*)(ap + t * 32);
    bf16x8 b0 = *(const bf16x8*)(bp + t * 32);
    bf16x8 b1 = *(const bf16x8*)(bp + o16 + t * 32);
    bf16x8 b2 = *(const bf16x8*)(bp + o32 + t * 32);
    bf16x8 b3 = *(const bf16x8*)(bp + o48 + t * 32);
    acc[0] = __builtin_amdgcn_mfma_f32_16x16x32_bf16(a, b0, acc[0], 0, 0, 0);
    acc[1] = __builtin_amdgcn_mfma_f32_16x16x32_bf16(a, b1, acc[1], 0, 0, 0);
    acc[2] = __builtin_amdgcn_mfma_f32_16x16x32_bf16(a, b2, acc[2], 0, 0, 0);
    acc[3] = __builtin_amdgcn_mfma_f32_16x16x32_bf16(a, b3, acc[3], 0, 0, 0);
  }
}

// ================= K1: prologue =================
// blocks [0,444): weight transpose tiles (LDS, coalesced both sides)
// blocks [444,1980): per-node pack + norms   (6144 waves)
// blocks [1980,2492): cross-modal sims       (2048 waves)
// blocks [2492,2504): zero d_out
__global__ __launch_bounds__(256) void pre_k(
    const float* __restrict__ xa, const float* __restrict__ xv, const float* __restrict__ xt,
    const float* __restrict__ fc0_w, const float* __restrict__ conv_w,
    const float* __restrict__ tm_w, const float* __restrict__ cross_w,
    short* __restrict__ fc0_wt, short* __restrict__ conv_wt, short* __restrict__ tm_wt,
    short* __restrict__ cross_wt, short* __restrict__ bigA, short* __restrict__ tmA,
    short* __restrict__ convA, short* __restrict__ hxb,
    float* __restrict__ inv_norm, float* __restrict__ cw, float* __restrict__ out) {
  __shared__ float tile[64][65];
  const int bx = blockIdx.x;
  const int lane = threadIdx.x & 63;
  const int wrp = threadIdx.x >> 6;

  if (bx < 444) {  // ---- weight transpose tile ----
    const float* src; short* dst; int srcK, KP, kt, ct;
    if (bx < 16) {
      src = fc0_w; dst = fc0_wt; srcK = 200; KP = 224; kt = bx >> 2; ct = bx & 3;
    } else if (bx < 156) {
      int b = (bx - 16) / 28, rem = (bx - 16) % 28;
      kt = rem >> 2; ct = rem & 3; srcK = 400; KP = 416;
      if (b < 2) { src = conv_w + b * 80000; dst = conv_wt + b * 86528; }
      else { src = tm_w + (b - 2) * 80000; dst = tm_wt + (b - 2) * 86528; }
    } else {
      int q = bx - 156, pp = q >> 4, rem = q & 15;
      kt = rem >> 2; ct = rem & 3; srcK = 200; KP = 224;
      src = cross_w + (pp / 3) * 120000 + (pp % 3) * 40000;
      dst = cross_wt + pp * (208 * 224);
    }
    const int k0 = kt * 64, c0 = ct * 64;
    #pragma unroll 4
    for (int r = 0; r < 16; r++) {
      int ky = r * 4 + wrp, k = k0 + ky, c = c0 + lane;
      tile[ky][lane] = (k < srcK && c < 200) ? src[k * 200 + c] : 0.f;
    }
    __syncthreads();
    #pragma unroll 4
    for (int r = 0; r < 16; r++) {
      int cy = r * 4 + wrp, c = c0 + cy, k = k0 + lane;
      if (c < 208 && k < KP) dst[c * KP + k] = f2bf(tile[lane][cy]);
    }
  } else if (bx < 1980) {  // ---- per-node pack + norm ----
    int u = (bx - 444) * 4 + wrp, m = u >> 11, a = u & 2047;
    const float* p = sel_mod(m, xa, xv, xt) + a * H;
    float v0 = p[lane], v1 = p[lane + 64], v2 = p[lane + 128];
    float v3 = (lane < 8) ? p[lane + 192] : 0.f;
    float s = v0 * v0 + v1 * v1 + v2 * v2 + v3 * v3;
    #pragma unroll
    for (int off = 32; off; off >>= 1) s += __shfl_down(s, off, 64);
    if (lane == 0) inv_norm[u] = 1.f / sqrtf(s);
    short b0 = f2bf(v0), b1 = f2bf(v1), b2 = f2bf(v2), b3 = f2bf(v3);
    short* br = bigA + u * 224;
    br[lane] = b0; br[lane + 64] = b1; br[lane + 128] = b2;
    if (lane < 32) br[192 + lane] = (lane < 8) ? b3 : (short)0;
    short* tr = tmA + u * 416;
    tr[lane] = b0; tr[lane + 64] = b1; tr[lane + 128] = b2;
    if (lane < 8) tr[192 + lane] = b3;
    if (lane < 16) { tr[400 + lane] = 0; convA[u * 416 + 400 + lane] = 0; }
    if (lane < 24) hxb[u * 224 + 200 + lane] = 0;
  } else if (bx < 2492) {  // ---- cross-modal sims ----
    int a = (bx - 1980) * 4 + wrp;
    const float* pa = xa + a * H;
    const float* pv = xv + a * H;
    const float* pt = xt + a * H;
    float a0 = pa[lane], a1 = pa[lane + 64], a2 = pa[lane + 128],
          a3 = (lane < 8) ? pa[lane + 192] : 0.f;
    float q0 = pv[lane], q1 = pv[lane + 64], q2 = pv[lane + 128],
          q3 = (lane < 8) ? pv[lane + 192] : 0.f;
    float t0 = pt[lane], t1 = pt[lane + 64], t2 = pt[lane + 128],
          t3 = (lane < 8) ? pt[lane + 192] : 0.f;
    float red[6];
    red[0] = a0 * a0 + a1 * a1 + a2 * a2 + a3 * a3;
    red[1] = q0 * q0 + q1 * q1 + q2 * q2 + q3 * q3;
    red[2] = t0 * t0 + t1 * t1 + t2 * t2 + t3 * t3;
    red[3] = a0 * q0 + a1 * q1 + a2 * q2 + a3 * q3;
    red[4] = a0 * t0 + a1 * t1 + a2 * t2 + a3 * t3;
    red[5] = q0 * t0 + q1 * t1 + q2 * t2 + q3 * t3;
    #pragma unroll
    for (int off = 32; off; off >>= 1)
      #pragma unroll
      for (int q = 0; q < 6; q++) red[q] += __shfl_down(red[q], off, 64);
    if (lane == 0) {
      float ia = 1.f / sqrtf(red[0]), iv = 1.f / sqrtf(red[1]), it = 1.f / sqrtf(red[2]);
      cw[a] = angsim(red[3] * ia * iv);
      cw[2048 + a] = angsim(red[4] * ia * it);
      cw[4096 + a] = angsim(red[5] * iv * it);
    }
  } else {  // ---- zero d_out (2048*6 floats) ----
    int i = (bx - 2492) * 1024 + threadIdx.x * 4;
    *(f32x4*)(out + i) = f32x4{0.f, 0.f, 0.f, 0.f};
  }
}

// ================= K2: intra Gram (+fused dinv, dinv-scaled output)  ||  fc0 =================
// blocks [0,96): intra; blocks [96,1344): fc0
__global__ __launch_bounds__(256) void intra_fc0_k(const short* __restrict__ bigA,
    const float* __restrict__ inv_norm, const float* __restrict__ cw,
    const short* __restrict__ fc0_wt, const float* __restrict__ bias,
    short* __restrict__ intra_s, float* __restrict__ dinv,
    short* __restrict__ convA, short* __restrict__ h_t) {
  __shared__ float sdinv[64];
  const int l = threadIdx.x & 63;
  const int w = threadIdx.x >> 6;
  if (blockIdx.x < 96) {
    const int mb = blockIdx.x;
    f32x4 acc[4] = {};
    gemm4<7>(bigA + (mb * 64 + w * 16) * 224, 224, bigA + mb * 64 * 224, 224, acc);
    const int fr = l & 15, fq = l >> 4;
    const int iL0 = w * 16 + fq * 4, u0 = mb * 64;
    float ang[4][4];
    float rsum[4] = {0.f, 0.f, 0.f, 0.f};
    #pragma unroll
    for (int j = 0; j < 4; j++) {
      float invj = inv_norm[u0 + j * 16 + fr];
      #pragma unroll
      for (int r = 0; r < 4; r++) {
        float av = angsim(acc[j][r] * inv_norm[u0 + iL0 + r] * invj);
        ang[j][r] = av;
        rsum[r] += av;
      }
    }
    #pragma unroll
    for (int mask = 1; mask < 16; mask <<= 1)
      #pragma unroll
      for (int r = 0; r < 4; r++) rsum[r] += __shfl_xor(rsum[r], mask, 64);
    if (fr == 0) {
      int m = u0 >> 11;
      #pragma unroll
      for (int r = 0; r < 4; r++) {
        int u = u0 + iL0 + r, a = u & 2047;
        float c1 = (m <= 1) ? cw[a] : cw[2048 + a];
        float c2 = (m == 0) ? cw[2048 + a] : cw[4096 + a];
        float dv = 1.f / sqrtf(rsum[r] + c1 + c2);
        dinv[u] = dv;
        sdinv[iL0 + r] = dv;
      }
    }
    __syncthreads();
    #pragma unroll
    for (int j = 0; j < 4; j++) {
      int jn = j * 16 + fr;
      float dj = sdinv[jn];
      #pragma unroll
      for (int r = 0; r < 4; r++)
        intra_s[mb * 4096 + (iL0 + r) * 64 + jn] = f2bf(ang[j][r] * sdinv[iL0 + r] * dj);
    }
  } else {
    const int bx2 = blockIdx.x - 96;
    const int c0 = (bx2 / 96) * 16;
    const int n0 = ((bx2 % 96) * 4 + w) * 16;
    f32x4 acc = {};
    gemm1<7>(fc0_wt + c0 * 224, 224, bigA + n0 * 224, 224, acc);
    const int node = n0 + (l & 15), cb = c0 + (l >> 4) * 4;
    if (cb >= 200) return;
    s16x4 oh;
    #pragma unroll
    for (int r = 0; r < 4; r++) {
      float v = fmaxf(acc[r] + bias[cb + r], 0.f);
      oh[r] = f2bf(v);
      h_t[(cb + r) * 6144 + node] = oh[r];
    }
    *(s16x4*)(convA + node * 416 + 200 + cb) = oh;
  }
}

// ================= K3/K5: adj (block-sparse, dinv pre-folded) =================
__global__ __launch_bounds__(256) void adj_g_k(const short* __restrict__ h_t,
    const short* __restrict__ intra_s, const float* __restrict__ cw,
    const float* __restrict__ dinv, short* __restrict__ convA) {
  const int mb = blockIdx.x, w = threadIdx.x >> 6;
  const int c0 = blockIdx.y * 16;
  const int nbase = mb * 64, ug = w * 16;
  f32x4 acc = {};
  gemm1<2>(h_t + c0 * 6144 + nbase, 6144, intra_s + mb * 4096 + ug * 64, 64, acc);
  const int l = threadIdx.x & 63;
  const int u = nbase + ug + (l & 15), cb = c0 + (l >> 4) * 4;
  if (cb >= 200) return;
  const int m = u >> 11, a = u & 2047;
  int n1, n2, p1, p2;
  if (m == 0)      { n1 = 1; p1 = 0; n2 = 2; p2 = 1; }
  else if (m == 1) { n1 = 0; p1 = 0; n2 = 2; p2 = 2; }
  else             { n1 = 0; p1 = 1; n2 = 1; p2 = 2; }
  float dv = dinv[u];
  int o1 = n1 * 2048 + a, o2 = n2 * 2048 + a;
  float w1 = cw[p1 * 2048 + a] * dv * dinv[o1];
  float w2 = cw[p2 * 2048 + a] * dv * dinv[o2];
  s16x4 o;
  #pragma unroll
  for (int r = 0; r < 4; r++) {
    int c = cb + r;
    float v = acc[r] + w1 * bf2f(h_t[c * 6144 + o1]) + w2 * bf2f(h_t[c * 6144 + o2]);
    o[r] = f2bf(v);
  }
  *(s16x4*)(convA + u * 416 + cb) = o;
}

// ================= K4/K6: GCNII combine =================
__global__ __launch_bounds__(256) void conv_g_k(const short* __restrict__ Wt,
    const short* __restrict__ convA, float beta, int writeHs,
    short* __restrict__ h_t, short* __restrict__ tmA) {
  const int w = threadIdx.x >> 6;
  const int c0 = blockIdx.y * 16;
  const int n0 = (blockIdx.x * 4 + w) * 16;
  f32x4 acc = {};
  gemm1<13>(Wt + c0 * 416, 416, convA + n0 * 416, 416, acc);
  const int l = threadIdx.x & 63;
  const int node = n0 + (l & 15), cb = c0 + (l >> 4) * 4;
  if (cb >= 200) return;
  s16x4 hiv = *(const s16x4*)(convA + node * 416 + cb);
  s16x4 h0v = *(const s16x4*)(convA + node * 416 + 200 + cb);
  float ombeta = 1.f - beta;
  if (writeHs) {
    #pragma unroll
    for (int r = 0; r < 4; r++) {
      float rr = 0.9f * bf2f(hiv[r]) + 0.1f * bf2f(h0v[r]);
      float v = fmaxf(beta * acc[r] + ombeta * rr, 0.f);
      h_t[(cb + r) * 6144 + node] = f2bf(v);
    }
  } else {
    s16x4 o;
    #pragma unroll
    for (int r = 0; r < 4; r++) {
      float rr = 0.9f * bf2f(hiv[r]) + 0.1f * bf2f(h0v[r]);
      float v = fmaxf(beta * acc[r] + ombeta * rr, 0.f);
      o[r] = f2bf(v);
    }
    *(s16x4*)(tmA + node * 416 + 200 + cb) = o;
  }
}

// ================= K7: tm =================
__global__ __launch_bounds__(256) void tm_g_k(const short* __restrict__ tm_wt,
    const short* __restrict__ tmA, const float* __restrict__ tmb, short* __restrict__ hxb) {
  const int m = blockIdx.z, w = threadIdx.x >> 6;
  const int c0 = blockIdx.y * 16;
  const int n0 = (blockIdx.x * 4 + w) * 16;
  f32x4 acc = {};
  gemm1<13>(tm_wt + m * (208 * 416) + c0 * 416, 416, tmA + (m * 2048 + n0) * 416, 416, acc);
  const int l = threadIdx.x & 63;
  const int node = n0 + (l & 15), cb = c0 + (l >> 4) * 4;
  if (cb >= 200) return;
  s16x4 o;
  #pragma unroll
  for (int r = 0; r < 4; r++) o[r] = f2bf(fmaxf(acc[r] + tmb[m * H + cb + r], 0.f));
  *(s16x4*)(hxb + (m * 2048 + node) * 224 + cb) = o;
}

// ================= K8: cross gate (3-phase) + fused final projection =================
__global__ __launch_bounds__(256) void crossg_g_k(const short* __restrict__ cross_wt,
    const short* __restrict__ hxb, const float* __restrict__ cb_,
    const float* __restrict__ uniw, const float* __restrict__ unib, float* __restrict__ out) {
  const int jm_t[6] = {1, 2, 0, 2, 0, 1};
  const int p = blockIdx.z, w = threadIdx.x >> 6;
  const int im = p >> 1, jm = jm_t[p];
  const int c0 = blockIdx.y * 16;
  const int n0 = (blockIdx.x * 4 + w) * 16;
  const short* Wp = cross_wt + p * (3 * 208 * 224);
  const short* Bi = hxb + (im * 2048 + n0) * 224;
  const short* Bj = hxb + (jm * 2048 + n0) * 224;
  f32x4 acc = {};
  gemm1<7>(Wp + c0 * 224, 224, Bi, 224, acc);
  gemm1<7>(Wp + 208 * 224 + c0 * 224, 224, Bj, 224, acc);
  {
    const int l = threadIdx.x & 63;
    const short* ap = Wp + 2 * 208 * 224 + (c0 + (l & 15)) * 224 + (l >> 4) * 8;
    const short* bpi = Bi + (l & 15) * 224 + (l >> 4) * 8;
    const short* bpj = Bj + (l & 15) * 224 + (l >> 4) * 8;
    #pragma unroll
    for (int t = 0; t < 7; t++) {
      bf16x8 a = *(const bf16x8*)(ap + t * 32);
      bf16x8 bi = *(const bf16x8*)(bpi + t * 32);
      bf16x8 bj = *(const bf16x8*)(bpj + t * 32);
      bf16x8 pr;
      #pragma unroll
      for (int e = 0; e < 8; e++) pr[e] = f2bf(bf2f(bi[e]) * bf2f(bj[e]));
      acc = __builtin_amdgcn_mfma_f32_16x16x32_bf16(a, pr, acc, 0, 0, 0);
    }
  }
  const int l = threadIdx.x & 63;
  const int node = n0 + (l & 15), cb = c0 + (l >> 4) * 4;
  float pt[6] = {0.f, 0.f, 0.f, 0.f, 0.f, 0.f};
  if (cb < 200) {
    s16x4 ai = *(const s16x4*)(hxb + (im * 2048 + node) * 224 + cb);
    s16x4 aj = *(const s16x4*)(hxb + (jm * 2048 + node) * 224 + cb);
    const float* Wu = uniw + im * (H * 6);
    #pragma unroll
    for (int r = 0; r < 4; r++) {
      float x = acc[r] + cb_[p * H + cb + r];
      float z = 1.f / (1.f + expf(-x));
      float o = z * bf2f(ai[r]) + (1.f - z) * bf2f(aj[r]);
      #pragma unroll
      for (int t = 0; t < 6; t++) pt[t] += o * Wu[(cb + r) * 6 + t];
    }
  }
  #pragma unroll
  for (int t = 0; t < 6; t++) {
    pt[t] += __shfl_xor(pt[t], 16, 64);
    pt[t] += __shfl_xor(pt[t], 32, 64);
  }
  if ((l >> 4) == 0) {
    if (p == 0 && blockIdx.y == 0) {
      #pragma unroll
      for (int t = 0; t < 6; t++) pt[t] += unib[t] + unib[6 + t] + unib[12 + t];
    }
    #pragma unroll
    for (int t = 0; t < 6; t++) atomicAdd(out + node * 6 + t, pt[t]);
  }
}

extern "C" void kernel_launch(void* const* d_in, const int* in_sizes, int n_in,
                              void* d_out, int out_size, void* d_ws, size_t ws_size,
                              hipStream_t stream) {
  const float* xa = (const float*)d_in[0];
  const float* xv = (const float*)d_in[1];
  const float* xt = (const float*)d_in[2];
  const float* fc0_w = (const float*)d_in[3];
  const float* fc0_b = (const float*)d_in[4];
  const float* conv_w = (const float*)d_in[5];
  const float* tm_w = (const float*)d_in[6];
  const float* tm_b = (const float*)d_in[7];
  const float* cross_w = (const float*)d_in[8];
  const float* cross_b = (const float*)d_in[9];
  const float* uni_w = (const float*)d_in[10];
  const float* uni_b = (const float*)d_in[11];
  float* out = (float*)d_out;
  float* ws = (float*)d_ws;

  float* inv_norm = ws;                       // 6144
  float* dinv = ws + 6144;                    // 6144
  float* cw = ws + 12288;                     // 6144
  short* bigA = (short*)(ws + 18432);         // 6144*224 sh -> 706560
  short* convA = (short*)(ws + 706560);       // 6144*416 sh -> 1984512
  short* tmA = (short*)(ws + 1984512);        // 6144*416 sh -> 3262464
  short* hxb = (short*)(ws + 3262464);        // 6144*224 sh -> 3950592
  short* h_t = (short*)(ws + 3950592);        // 208*6144 sh -> 4589568
  short* intra_s = (short*)(ws + 4589568);    // 96*4096 sh -> 4786176
  short* fc0_wt = (short*)(ws + 4786176);     // 208*224 sh -> 4809472
  short* conv_wt = (short*)(ws + 4809472);    // 2*208*416 sh -> 4896000
  short* tm_wt = (short*)(ws + 4896000);      // 3*208*416 sh -> 5025792
  short* cross_wt = (short*)(ws + 5025792);   // 18*208*224 sh -> 5445120

  pre_k<<<2504, 256, 0, stream>>>(xa, xv, xt, fc0_w, conv_w, tm_w, cross_w,
                                  fc0_wt, conv_wt, tm_wt, cross_wt,
                                  bigA, tmA, convA, hxb, inv_norm, cw, out);
  intra_fc0_k<<<1344, 256, 0, stream>>>(bigA, inv_norm, cw, fc0_wt, fc0_b,
                                        intra_s, dinv, convA, h_t);
  adj_g_k<<<dim3(96, 13), 256, 0, stream>>>(h_t, intra_s, cw, dinv, convA);
  conv_g_k<<<dim3(96, 13), 256, 0, stream>>>(conv_wt, convA,
                                             0.40546510810816444f, 1, h_t, tmA);
  adj_g_k<<<dim3(96, 13), 256, 0, stream>>>(h_t, intra_s, cw, dinv, convA);
  conv_g_k<<<dim3(96, 13), 256, 0, stream>>>(conv_wt + 208 * 416, convA,
                                             0.22314355131420976f, 0, h_t, tmA);
  tm_g_k<<<dim3(32, 13, 3), 256, 0, stream>>>(tm_wt, tmA, tm_b, hxb);
  crossg_g_k<<<dim3(32, 13, 6), 256, 0, stream>>>(cross_wt, hxb, cross_b, uni_w, uni_b, out);
}